// Round 7
// baseline (1089.302 us; speedup 1.0000x reference)
//
#include <hip/hip_runtime.h>
#include <hip/hip_bf16.h>

// DecoderBlock: B=4, S=2048, D=1024, DFF=4096. fp32 in/out, bf16 MFMA internals.
// Round 7: k_gemmW — 256 threads / 4 waves, 256x128 tile, per-wave 128x64,
// BK=32, 48 KB LDS -> 3 blocks/CU (m97 co-residency regime), simple
// syncthreads+stage+read+MFMA loop. Single-variable experiment: occupancy.

#define Bb 4
#define Ss 2048
#define Dd 1024
#define Ff 4096

typedef __attribute__((ext_vector_type(4))) float f32x4;
typedef __attribute__((ext_vector_type(8))) short bf16x8;
typedef __attribute__((ext_vector_type(8))) unsigned short u16x8;
typedef __attribute__((ext_vector_type(4))) unsigned short u16x4;

__device__ __forceinline__ unsigned short f2bf(float f) {
  unsigned u = __float_as_uint(f);
  u += 0x7FFFu + ((u >> 16) & 1u);
  return (unsigned short)(u >> 16);
}
__device__ __forceinline__ float bf2f(unsigned short h) {
  return __uint_as_float(((unsigned)h) << 16);
}

__device__ __forceinline__ void gload_lds16(const void* g, void* l) {
  __builtin_amdgcn_global_load_lds((const __attribute__((address_space(1))) void*)g,
                                   (__attribute__((address_space(3))) void*)l, 16, 0, 0);
}

__device__ __forceinline__ int xcd8(int orig, int n) {
  int q = n >> 3, r = n & 7;
  int x = orig & 7;
  int base = x < r ? x * (q + 1) : r * (q + 1) + (x - r) * q;
  return base + (orig >> 3);
}

// ---------------- transpose+cast: in[R][C] fp32 -> outT[C][R] bf16 (+opt outR bf16) ----
__global__ __launch_bounds__(256) void k_transpose_cast(const float* __restrict__ in,
                                                        unsigned short* __restrict__ outT,
                                                        unsigned short* __restrict__ outR,
                                                        int R, int C) {
  __shared__ float t[32][33];
  size_t bo = (size_t)blockIdx.z * R * C;
  const float* pin = in + bo;
  unsigned short* poutT = outT + bo;
  unsigned short* poutR = outR ? outR + bo : nullptr;
  int c0 = blockIdx.x * 32, r0 = blockIdx.y * 32;
  int tx = threadIdx.x, ty = threadIdx.y;
#pragma unroll
  for (int i = 0; i < 4; i++) {
    float v = pin[(size_t)(r0 + ty + i * 8) * C + c0 + tx];
    t[ty + i * 8][tx] = v;
    if (poutR) poutR[(size_t)(r0 + ty + i * 8) * C + c0 + tx] = f2bf(v);
  }
  __syncthreads();
#pragma unroll
  for (int i = 0; i < 4; i++)
    poutT[(size_t)(c0 + ty + i * 8) * R + r0 + tx] = f2bf(t[tx][ty + i * 8]);
}

// =========================================================================
// k_gemmW: C = A(MxK) * Bt(NxK)^T, bf16 in, fp32 acc.
// Tile 256(M) x 128(N), BK=32, 256 threads = 4 waves (2M x 2N), per-wave
// 128x64 (8 m-frags x 4 n-frags of 16x16x32). LDS 48 KB dbuf -> 3 blocks/CU.
// Rows are 64 B (32 bf16); swizzle: phys 16B-chunk p at row r holds logical
// p^(r&3); staging writes linear with inverse-swizzled global source.
// EPI: 0 *scale->bf16 | 2 bias+relu->bf16 | 4 v+resid->fp32 | 5 v+bias+resid
// CAUSAL: triangular grid over 256x128 tiles (2ti+2 blocks per row-stripe).
// KCAP: nk capped at i0/32+8 (P zeroed past diagonal by softmax).
// =========================================================================
#define PRIO1() __builtin_amdgcn_s_setprio(1)
#define PRIO0() __builtin_amdgcn_s_setprio(0)

template <int EPI, bool CAUSAL, bool KCAP>
__global__ __launch_bounds__(256, 3) void k_gemmW(
    const unsigned short* __restrict__ Ag, const unsigned short* __restrict__ Bg,
    float* __restrict__ Cf, unsigned short* __restrict__ Cb,
    const float* __restrict__ bias, const float* __restrict__ resid,
    int K, int lda, int ldb, int ldc, long bsA, long bsB, long bsC, float scale) {
  constexpr int ABY = 256 * 64;  // 16 KB: one A buffer (256 rows x 32 bf16)
  constexpr int BBY = 128 * 64;  // 8 KB: one B buffer
  __shared__ alignas(16) char lds[2 * ABY + 2 * BBY];  // 48 KB

  int i0, j0;
  if (CAUSAL) {
    // row-stripe ti (256 rows) has 2*ti+2 col-blocks (128 wide); cum = ti*(ti+1)
    int t = xcd8(blockIdx.x, gridDim.x);
    int ti = (int)((sqrtf(4.f * t + 1.f) - 1.f) * 0.5f);
    while ((ti + 1) * (ti + 2) <= t) ++ti;
    while (ti * (ti + 1) > t) --ti;
    i0 = ti * 256;
    j0 = (t - ti * (ti + 1)) * 128;
  } else {
    int lin = xcd8(blockIdx.y * gridDim.x + blockIdx.x, gridDim.x * gridDim.y);
    i0 = (lin / gridDim.x) * 256;
    j0 = (lin % gridDim.x) * 128;
  }
  int bz = blockIdx.z;
  Ag += (size_t)bz * bsA;
  Bg += (size_t)bz * bsB;

  int nk = K / 32;
  if (KCAP) {
    int cap = i0 / 32 + 8;
    nk = nk < cap ? nk : cap;
  }

  const int tid = threadIdx.x;
  const int w = tid >> 6, lane = tid & 63;
  const int wr = w >> 1, wc = w & 1;

  // ---- staging: thread t covers (row tr = t>>2, phys chunk tc = t&3) per
  // 64-row group; source logical chunk = tc ^ (tr&3) (inverse swizzle).
  const int tr = tid >> 2, tc = tid & 3;
  const int scs = tc ^ (tr & 3);
  const unsigned short* As = Ag + (size_t)(i0 + tr) * lda + scs * 8;
  const unsigned short* Bs = Bg + (size_t)(j0 + tr) * ldb + scs * 8;
  char* ldsA = lds + tid * 16;
  char* ldsB = lds + 2 * ABY + tid * 16;

  auto stage = [&](int kt) {
    int ks = kt < nk ? kt : nk - 1;
    int boA = (kt & 1) * ABY, boB = (kt & 1) * BBY;
#pragma unroll
    for (int i = 0; i < 4; ++i)
      gload_lds16(As + (size_t)(i * 64) * lda + ks * 32, ldsA + boA + i * 4096);
#pragma unroll
    for (int i = 0; i < 2; ++i)
      gload_lds16(Bs + (size_t)(i * 64) * ldb + ks * 32, ldsB + boB + i * 4096);
  };

  // ---- swizzled read offsets: logical chunk kq at row r -> phys kq^(r&3).
  // mi*16 rows keep (r&3) invariant -> frag mi = base + mi*1024.
  const int fr = lane & 15, kq = lane >> 4;
  const int rA = wr * 128 + fr;
  const int rB = wc * 64 + fr;
  const unsigned aof = rA * 64 + ((kq ^ (rA & 3)) << 4);
  const unsigned bof = rB * 64 + ((kq ^ (rB & 3)) << 4);

  f32x4 acc[8][4];
#pragma unroll
  for (int m = 0; m < 8; ++m)
#pragma unroll
    for (int n = 0; n < 4; ++n) acc[m][n] = (f32x4){0.f, 0.f, 0.f, 0.f};

  stage(0);
  for (int kt = 0; kt < nk; ++kt) {
    __syncthreads();  // compiler drains vmcnt/lgkm: buf(kt) staged, buf^1 reads done
    if (kt + 1 < nk) stage(kt + 1);
    const char* pA = lds + (kt & 1) * ABY + aof;
    const char* pB = lds + 2 * ABY + (kt & 1) * BBY + bof;
    bf16x8 a[8], b[4];
#pragma unroll
    for (int mi = 0; mi < 8; ++mi) a[mi] = *(const bf16x8*)(pA + mi * 1024);
#pragma unroll
    for (int ni = 0; ni < 4; ++ni) b[ni] = *(const bf16x8*)(pB + ni * 1024);
    PRIO1();
#pragma unroll
    for (int mi = 0; mi < 8; ++mi)
#pragma unroll
      for (int ni = 0; ni < 4; ++ni)
        acc[mi][ni] = __builtin_amdgcn_mfma_f32_16x16x32_bf16(a[mi], b[ni], acc[mi][ni], 0, 0, 0);
    PRIO0();
  }

  // ---- epilogue: C[row=(lane>>4)*4+r][col=lane&15] per 16x16 frag ----
  const int colb = j0 + wc * 64 + fr;
  const int rowb = i0 + wr * 128 + (kq << 2);
  const size_t cb = (size_t)bz * bsC;
#pragma unroll
  for (int m = 0; m < 8; ++m) {
#pragma unroll
    for (int r = 0; r < 4; ++r) {
      size_t ro = cb + (size_t)(rowb + m * 16 + r) * ldc;
#pragma unroll
      for (int n = 0; n < 4; ++n) {
        float v = acc[m][n][r];
        int col = colb + n * 16;
        if (EPI == 0) Cb[ro + col] = f2bf(v * scale);
        else if (EPI == 2) Cb[ro + col] = f2bf(fmaxf(v + bias[col], 0.f));
        else if (EPI == 4) Cf[ro + col] = v + resid[ro + col];
        else Cf[ro + col] = v + bias[col] + resid[ro + col];
      }
    }
  }
}

// ---------------- row softmax, bf16 scores -> bf16 P in place ----------------
// CAUSAL: touch only the 256-aligned stripe span [0, (i&~255)+256) — matches
// PV1's KCAP read range (nk = i0/32+8 over 256-row stripes).
template <bool CAUSAL>
__global__ __launch_bounds__(256) void k_softmax(unsigned short* __restrict__ scores) {
  int row = blockIdx.x;  // b*S + i
  int i = row & (Ss - 1);
  unsigned short* src = scores + (size_t)row * Ss;
  int nv = CAUSAL ? i + 1 : Ss;
  int nb = CAUSAL ? ((i & ~255) + 256) : Ss;
  int t = threadIdx.x;
  int w = t >> 6, lane = t & 63;
  bool act = t * 8 < nb;
  float v[8];
  float mx = -1e30f;
  if (act) {
    u16x8 raw = *(const u16x8*)(src + t * 8);
#pragma unroll
    for (int k = 0; k < 8; k++) {
      int j = t * 8 + k;
      v[k] = (j < nv) ? bf2f(raw[k]) : -1e30f;
      mx = fmaxf(mx, v[k]);
    }
  } else {
#pragma unroll
    for (int k = 0; k < 8; k++) v[k] = -1e30f;
  }
#pragma unroll
  for (int o = 32; o; o >>= 1) mx = fmaxf(mx, __shfl_xor(mx, o));
  __shared__ float red[8];
  if (lane == 0) red[w] = mx;
  __syncthreads();
  mx = fmaxf(fmaxf(red[0], red[1]), fmaxf(red[2], red[3]));
  float sum = 0.f;
#pragma unroll
  for (int k = 0; k < 8; k++) {
    float e = (v[k] > -1e29f) ? __expf(v[k] - mx) : 0.f;
    v[k] = e;
    sum += e;
  }
#pragma unroll
  for (int o = 32; o; o >>= 1) sum += __shfl_xor(sum, o);
  if (lane == 0) red[4 + w] = sum;
  __syncthreads();
  sum = red[4] + red[5] + red[6] + red[7];
  float inv = 1.f / sum;
  if (act) {
    u16x8 r;
#pragma unroll
    for (int k = 0; k < 8; k++) r[k] = f2bf(v[k] * inv);
    *(u16x8*)(src + t * 8) = r;
  }
}

// ---------------- LayerNorm (input already has residual added) ----------------
__global__ __launch_bounds__(256) void k_ln(const float* __restrict__ a,
                                            const float* __restrict__ g,
                                            const float* __restrict__ be,
                                            float* __restrict__ outf,
                                            unsigned short* __restrict__ outb) {
  int row = blockIdx.x;
  size_t o = (size_t)row * Dd;
  int t = threadIdx.x;
  f32x4 x = *(const f32x4*)(a + o + t * 4);
  float s = x[0] + x[1] + x[2] + x[3];
  float q = x[0] * x[0] + x[1] * x[1] + x[2] * x[2] + x[3] * x[3];
  int w = t >> 6, lane = t & 63;
#pragma unroll
  for (int of = 32; of; of >>= 1) {
    s += __shfl_xor(s, of);
    q += __shfl_xor(q, of);
  }
  __shared__ float red[8];
  if (lane == 0) {
    red[w] = s;
    red[4 + w] = q;
  }
  __syncthreads();
  s = red[0] + red[1] + red[2] + red[3];
  q = red[4] + red[5] + red[6] + red[7];
  float mean = s * (1.f / Dd);
  float var = q * (1.f / Dd) - mean * mean;
  float rstd = rsqrtf(var + 1e-5f);
  f32x4 gv = *(const f32x4*)(g + t * 4);
  f32x4 bv = *(const f32x4*)(be + t * 4);
  f32x4 y;
#pragma unroll
  for (int k = 0; k < 4; k++) y[k] = (x[k] - mean) * rstd * gv[k] + bv[k];
  *(f32x4*)(outf + o + t * 4) = y;
  if (outb) {
    u16x4 r;
    r[0] = f2bf(y[0]); r[1] = f2bf(y[1]); r[2] = f2bf(y[2]); r[3] = f2bf(y[3]);
    *(u16x4*)(outb + o + t * 4) = r;
  }
}

extern "C" void kernel_launch(void* const* d_in, const int* in_sizes, int n_in, void* d_out,
                              int out_size, void* d_ws, size_t ws_size, hipStream_t stream) {
  (void)in_sizes; (void)n_in; (void)out_size; (void)ws_size;
  const float* y   = (const float*)d_in[0];
  const float* Z   = (const float*)d_in[1];
  const float* w1  = (const float*)d_in[2];
  const float* b1  = (const float*)d_in[3];
  const float* w2  = (const float*)d_in[4];
  const float* b2  = (const float*)d_in[5];
  const float* g1  = (const float*)d_in[6];
  const float* be1 = (const float*)d_in[7];
  const float* g2  = (const float*)d_in[8];
  const float* be2 = (const float*)d_in[9];
  const float* g3  = (const float*)d_in[10];
  const float* be3 = (const float*)d_in[11];
  float* out = (float*)d_out;

  char* ws = (char*)d_ws;
  const size_t MB = 1024ull * 1024ull;
  unsigned short* T   = (unsigned short*)(ws);            // y^T then Z^T (bf16)
  unsigned short* Zbf = (unsigned short*)(ws + 16 * MB);  // Z bf16
  unsigned short* ybf = (unsigned short*)(ws + 32 * MB);  // y / y1 / y2 bf16
  unsigned short* w1t = (unsigned short*)(ws + 48 * MB);  // w1^T bf16
  unsigned short* w2t = (unsigned short*)(ws + 56 * MB);  // w2^T bf16
  unsigned short* sc  = (unsigned short*)(ws + 64 * MB);  // scores/P bf16 (32MB)
  unsigned short* h   = (unsigned short*)(ws + 64 * MB);  // h bf16 (64MB) aliases dead sc
  float* res          = (float*)(ws + 128 * MB);          // residual stream fp32
  float* attn         = (float*)d_out;                    // attn / ff scratch

  dim3 b256(256);
  const float scl = 1.f / 32.f;
  const long SD = (long)Ss * Dd, SS = (long)Ss * Ss;

  // --- self-attention ---
  k_transpose_cast<<<dim3(Dd / 32, Ss / 32, Bb), dim3(32, 8), 0, stream>>>(y, T, ybf, Ss, Dd);
  k_gemmW<0, true, false><<<dim3(72, 1, Bb), b256, 0, stream>>>(
      ybf, ybf, nullptr, sc, nullptr, nullptr, Dd, Dd, Dd, Ss, SD, SD, SS, scl);
  k_softmax<true><<<dim3(Bb * Ss), b256, 0, stream>>>(sc);
  k_gemmW<4, false, true><<<dim3(Dd / 128, Ss / 256, Bb), b256, 0, stream>>>(
      sc, T, attn, nullptr, nullptr, y, Ss, Ss, Ss, Dd, SS, SD, SD, 1.f);
  k_ln<<<dim3(Bb * Ss), b256, 0, stream>>>(attn, g1, be1, res, ybf);

  // --- cross-attention ---
  k_transpose_cast<<<dim3(Dd / 32, Ss / 32, Bb), dim3(32, 8), 0, stream>>>(Z, T, Zbf, Ss, Dd);
  k_gemmW<0, false, false><<<dim3(Ss / 128, Ss / 256, Bb), b256, 0, stream>>>(
      ybf, Zbf, nullptr, sc, nullptr, nullptr, Dd, Dd, Dd, Ss, SD, SD, SS, scl);
  k_softmax<false><<<dim3(Bb * Ss), b256, 0, stream>>>(sc);
  k_gemmW<4, false, false><<<dim3(Dd / 128, Ss / 256, Bb), b256, 0, stream>>>(
      sc, T, attn, nullptr, nullptr, res, Ss, Ss, Ss, Dd, SS, SD, SD, 1.f);
  k_ln<<<dim3(Bb * Ss), b256, 0, stream>>>(attn, g2, be2, res, ybf);

  // --- FFN ---
  k_transpose_cast<<<dim3(Ff / 32, Dd / 32, 1), dim3(32, 8), 0, stream>>>(w1, w1t, nullptr, Dd, Ff);
  k_transpose_cast<<<dim3(Dd / 32, Ff / 32, 1), dim3(32, 8), 0, stream>>>(w2, w2t, nullptr, Ff, Dd);
  k_gemmW<2, false, false><<<dim3(Ff / 128, (Bb * Ss) / 256, 1), b256, 0, stream>>>(
      ybf, w1t, nullptr, h, b1, nullptr, Dd, Dd, Dd, Ff, 0L, 0L, 0L, 1.f);
  k_gemmW<5, false, false><<<dim3(Dd / 128, (Bb * Ss) / 256, 1), b256, 0, stream>>>(
      h, w2t, attn, nullptr, b2, res, Ff, Ff, Ff, Dd, 0L, 0L, 0L, 1.f);
  k_ln<<<dim3(Bb * Ss), b256, 0, stream>>>(attn, g3, be3, out, nullptr);
}

// Round 8
// 378.887 us; speedup vs baseline: 2.8750x; 2.8750x over previous
//
#include <hip/hip_runtime.h>
#include <hip/hip_bf16.h>

// DecoderBlock: B=4, S=2048, D=1024, DFF=4096. fp32 in/out, bf16 MFMA internals.
// Round 8: revert GEMMs to R6 (known-good 8-phase/4-phase); hoist all input
// transposes to stream start (Z^T in its own aliased slot); bf16 LN input path
// (EPI4/5 -> bf16, k_ln reads bf16). No GEMM-schedule changes.

#define Bb 4
#define Ss 2048
#define Dd 1024
#define Ff 4096

typedef __attribute__((ext_vector_type(4))) float f32x4;
typedef __attribute__((ext_vector_type(8))) short bf16x8;
typedef __attribute__((ext_vector_type(8))) unsigned short u16x8;
typedef __attribute__((ext_vector_type(4))) unsigned short u16x4;

__device__ __forceinline__ unsigned short f2bf(float f) {
  unsigned u = __float_as_uint(f);
  u += 0x7FFFu + ((u >> 16) & 1u);
  return (unsigned short)(u >> 16);
}
__device__ __forceinline__ float bf2f(unsigned short h) {
  return __uint_as_float(((unsigned)h) << 16);
}

__device__ __forceinline__ void gload_lds16(const void* g, void* l) {
  __builtin_amdgcn_global_load_lds((const __attribute__((address_space(1))) void*)g,
                                   (__attribute__((address_space(3))) void*)l, 16, 0, 0);
}

__device__ __forceinline__ int xcd8(int orig, int n) {
  int q = n >> 3, r = n & 7;
  int x = orig & 7;
  int base = x < r ? x * (q + 1) : r * (q + 1) + (x - r) * q;
  return base + (orig >> 3);
}

// ---------------- transpose+cast: in[R][C] fp32 -> outT[C][R] bf16 (+opt outR bf16) ----
__global__ __launch_bounds__(256) void k_transpose_cast(const float* __restrict__ in,
                                                        unsigned short* __restrict__ outT,
                                                        unsigned short* __restrict__ outR,
                                                        int R, int C) {
  __shared__ float t[32][33];
  size_t bo = (size_t)blockIdx.z * R * C;
  const float* pin = in + bo;
  unsigned short* poutT = outT + bo;
  unsigned short* poutR = outR ? outR + bo : nullptr;
  int c0 = blockIdx.x * 32, r0 = blockIdx.y * 32;
  int tx = threadIdx.x, ty = threadIdx.y;
#pragma unroll
  for (int i = 0; i < 4; i++) {
    float v = pin[(size_t)(r0 + ty + i * 8) * C + c0 + tx];
    t[ty + i * 8][tx] = v;
    if (poutR) poutR[(size_t)(r0 + ty + i * 8) * C + c0 + tx] = f2bf(v);
  }
  __syncthreads();
#pragma unroll
  for (int i = 0; i < 4; i++)
    poutT[(size_t)(c0 + ty + i * 8) * R + r0 + tx] = f2bf(t[tx][ty + i * 8]);
}

// ---- shared GEMM machinery --------------------------------------------------
// EPI: 0 *scale->bf16 | 2 bias+relu->bf16 | 4 (v+resid)->bf16 | 5 (v+bias+resid)->bf16
#define BAR() __builtin_amdgcn_s_barrier()
#define PRIO1() __builtin_amdgcn_s_setprio(1)
#define PRIO0() __builtin_amdgcn_s_setprio(0)
#define LGKM0()                                          \
  {                                                      \
    asm volatile("s_waitcnt lgkmcnt(0)" ::: "memory");   \
    __builtin_amdgcn_sched_barrier(0);                   \
  }

#define LDA8(arr, mh, bo)                                                       \
  {                                                                             \
    _Pragma("unroll") for (int j_ = 0; j_ < QM; ++j_) {                         \
      _Pragma("unroll") for (int kh_ = 0; kh_ < 2; ++kh_) {                     \
        arr[j_][kh_] =                                                          \
            *(const bf16x8*)(lds + (bo) + ((mh)*QM + j_) * 2048 + aof[kh_]);    \
      }                                                                         \
    }                                                                           \
  }

#define LDB8(arr, nh, bo)                                                       \
  {                                                                             \
    _Pragma("unroll") for (int n_ = 0; n_ < 2; ++n_) {                          \
      _Pragma("unroll") for (int kh_ = 0; kh_ < 2; ++kh_) {                     \
        arr[n_][kh_] =                                                          \
            *(const bf16x8*)(lds + (bo) + ((nh)*2 + n_) * 2048 + bof[kh_]);     \
      }                                                                         \
    }                                                                           \
  }

#define MMQ(aarr, barr, mh, nh)                                                 \
  {                                                                             \
    _Pragma("unroll") for (int j_ = 0; j_ < QM; ++j_) {                         \
      _Pragma("unroll") for (int n_ = 0; n_ < 2; ++n_) {                        \
        _Pragma("unroll") for (int kh_ = 0; kh_ < 2; ++kh_) {                   \
          acc[(mh)*QM + j_][(nh)*2 + n_] = __builtin_amdgcn_mfma_f32_16x16x32_bf16( \
              aarr[j_][kh_], barr[n_][kh_], acc[(mh)*QM + j_][(nh)*2 + n_], 0, 0, 0); \
        }                                                                       \
      }                                                                         \
    }                                                                           \
  }

#define EPILOGUE(MR_, WMS_)                                                     \
  {                                                                             \
    const int colb = j0 + wc * 64 + fr;                                         \
    const int rowb = i0 + wr * (WMS_) + (kq << 2);                              \
    const size_t cb = (size_t)bz * bsC;                                         \
    _Pragma("unroll") for (int m = 0; m < (MR_); ++m) {                         \
      _Pragma("unroll") for (int r = 0; r < 4; ++r) {                           \
        size_t ro = cb + (size_t)(rowb + m * 16 + r) * ldc;                     \
        _Pragma("unroll") for (int n = 0; n < 4; ++n) {                         \
          float v = acc[m][n][r];                                               \
          int col = colb + n * 16;                                              \
          if (EPI == 0) Cb[ro + col] = f2bf(v * scale);                         \
          else if (EPI == 2) Cb[ro + col] = f2bf(fmaxf(v + bias[col], 0.f));    \
          else if (EPI == 4) Cb[ro + col] = f2bf(v + resid[ro + col]);          \
          else Cb[ro + col] = f2bf(v + bias[col] + resid[ro + col]);            \
        }                                                                       \
      }                                                                         \
    }                                                                           \
  }

// ========================= k_gemm8: BMt=256, 8-phase (R6 geometry) ===========
template <int EPI, bool CAUSAL>
__global__ __launch_bounds__(512) void k_gemm8(
    const unsigned short* __restrict__ Ag, const unsigned short* __restrict__ Bg,
    unsigned short* __restrict__ Cb,
    const float* __restrict__ bias, const float* __restrict__ resid,
    int K, int lda, int ldb, int ldc, long bsA, long bsB, long bsC, float scale) {
  constexpr int QM = 4;
  constexpr int ABYTES = 32768, BBYTES = 32768;
  __shared__ alignas(16) char lds[2 * ABYTES + 2 * BBYTES];

  int i0, j0;
  if (CAUSAL) {
    int t = xcd8(blockIdx.x, gridDim.x);
    int ti = (int)((sqrtf(8.f * t + 1.f) - 1.f) * 0.5f);
    while ((ti + 1) * (ti + 2) / 2 <= t) ++ti;
    while (ti * (ti + 1) / 2 > t) --ti;
    i0 = ti * 256;
    j0 = (t - ti * (ti + 1) / 2) * 256;
  } else {
    int lin = xcd8(blockIdx.y * gridDim.x + blockIdx.x, gridDim.x * gridDim.y);
    i0 = (lin / gridDim.x) * 256;
    j0 = (lin % gridDim.x) * 256;
  }
  int bz = blockIdx.z;
  Ag += (size_t)bz * bsA;
  Bg += (size_t)bz * bsB;

  const int nk = K / 64;
  const int niter = nk / 2;

  const int tid = threadIdx.x;
  const int w = tid >> 6, lane = tid & 63;
  const int wr = w >> 2, wc = w & 3;

  const int srow = (w << 3) + (lane >> 3);
  const int bcs = (lane & 7) ^ (lane >> 3);
  const unsigned short* As = Ag + (size_t)(i0 + srow) * lda + bcs * 8;
  const unsigned short* Bs = Bg + (size_t)(j0 + srow) * ldb + bcs * 8;
  char* ldsAw = lds + w * 1024;
  char* ldsBw = lds + 2 * ABYTES + w * 1024;

  auto stA = [&](int kt, int hf) {
    int ks = kt < nk ? kt : nk - 1;
#pragma unroll
    for (int l = 0; l < 2; ++l)
      gload_lds16(As + (size_t)(hf * 128 + l * 64) * lda + ks * 64,
                  ldsAw + (kt & 1) * ABYTES + hf * 128 * 128 + l * 8192);
  };
  auto stB = [&](int kt, int hf) {
    int ks = kt < nk ? kt : nk - 1;
#pragma unroll
    for (int l = 0; l < 2; ++l)
      gload_lds16(Bs + (size_t)(hf * 128 + l * 64) * ldb + ks * 64,
                  ldsBw + (kt & 1) * BBYTES + hf * 128 * 128 + l * 8192);
  };

  const int fr = lane & 15, kq = lane >> 4;
  const int rA = wr * 128 + fr;
  const int rB = wc * 64 + fr;
  unsigned aof[2], bof[2];
  aof[0] = rA * 128 + ((kq ^ (rA & 7)) << 4);
  aof[1] = rA * 128 + (((kq + 4) ^ (rA & 7)) << 4);
  bof[0] = 2 * ABYTES + rB * 128 + ((kq ^ (rB & 7)) << 4);
  bof[1] = 2 * ABYTES + rB * 128 + (((kq + 4) ^ (rB & 7)) << 4);
  constexpr int A0 = 0, A1 = ABYTES, B0 = 0, B1 = BBYTES;

  f32x4 acc[8][4];
#pragma unroll
  for (int m = 0; m < 8; ++m)
#pragma unroll
    for (int n = 0; n < 4; ++n) acc[m][n] = (f32x4){0.f, 0.f, 0.f, 0.f};

  bf16x8 a0[QM][2], a1[QM][2], b0[2][2], b1[2][2];

  stA(0, 0); stA(0, 1); stB(0, 0); stB(0, 1);
  stA(1, 0); stA(1, 1); stB(1, 0);
  asm volatile("s_waitcnt vmcnt(6)" ::: "memory");
  BAR();

  for (int t = 0; t < niter; ++t) {
    const int ka = 2 * t + 2, kb = 2 * t + 3;
    LDA8(a0, 0, A0); LDB8(b0, 0, B0);
    stB(2 * t + 1, 1);
    BAR(); LGKM0(); PRIO1(); MMQ(a0, b0, 0, 0); PRIO0(); BAR();
    LDA8(a1, 1, A0);
    stA(ka, 0);
    BAR(); LGKM0(); PRIO1(); MMQ(a1, b0, 1, 0); PRIO0(); BAR();
    LDB8(b1, 1, B0);
    stA(ka, 1);
    BAR(); LGKM0(); PRIO1(); MMQ(a1, b1, 1, 1); PRIO0(); BAR();
    stB(ka, 0);
    asm volatile("s_waitcnt vmcnt(6)" ::: "memory");
    BAR(); PRIO1(); MMQ(a0, b1, 0, 1); PRIO0(); BAR();
    LDA8(a0, 0, A1); LDB8(b0, 0, B1);
    stB(ka, 1);
    BAR(); LGKM0(); PRIO1(); MMQ(a0, b0, 0, 0); PRIO0(); BAR();
    LDA8(a1, 1, A1);
    stA(kb, 0);
    BAR(); LGKM0(); PRIO1(); MMQ(a1, b0, 1, 0); PRIO0(); BAR();
    LDB8(b1, 1, B1);
    stA(kb, 1);
    BAR(); LGKM0(); PRIO1(); MMQ(a1, b1, 1, 1); PRIO0(); BAR();
    stB(kb, 0);
    asm volatile("s_waitcnt vmcnt(6)" ::: "memory");
    BAR(); PRIO1(); MMQ(a0, b1, 0, 1); PRIO0(); BAR();
  }
  EPILOGUE(8, 128)
}

// ========================= k_gemm4: BMt=128, 4-phase (R6 geometry) ===========
template <int EPI, bool KCAP>
__global__ __launch_bounds__(512) void k_gemm4(
    const unsigned short* __restrict__ Ag, const unsigned short* __restrict__ Bg,
    unsigned short* __restrict__ Cb,
    const float* __restrict__ bias, const float* __restrict__ resid,
    int K, int lda, int ldb, int ldc, long bsA, long bsB, long bsC, float scale) {
  constexpr int QM = 4;
  constexpr int ABYTES = 16384, BBYTES = 32768;
  __shared__ alignas(16) char lds[2 * ABYTES + 2 * BBYTES];

  int lin = xcd8(blockIdx.y * gridDim.x + blockIdx.x, gridDim.x * gridDim.y);
  int i0 = (lin / gridDim.x) * 128;
  int j0 = (lin % gridDim.x) * 256;
  int bz = blockIdx.z;
  Ag += (size_t)bz * bsA;
  Bg += (size_t)bz * bsB;

  int nk = K / 64;
  if (KCAP) {
    int cap = i0 / 64 + 2;
    nk = nk < cap ? nk : cap;
  }
  const int niter = nk / 2;

  const int tid = threadIdx.x;
  const int w = tid >> 6, lane = tid & 63;
  const int wr = w >> 2, wc = w & 3;

  const int srow = (w << 3) + (lane >> 3);
  const int bcs = (lane & 7) ^ (lane >> 3);
  const unsigned short* As = Ag + (size_t)(i0 + srow) * lda + bcs * 8;
  const unsigned short* Bs = Bg + (size_t)(j0 + srow) * ldb + bcs * 8;
  char* ldsAw = lds + w * 1024;
  char* ldsBw = lds + 2 * ABYTES + w * 1024;

  auto stA2 = [&](int kt) {
    int ks = kt < nk ? kt : nk - 1;
#pragma unroll
    for (int hf = 0; hf < 2; ++hf)
      gload_lds16(As + (size_t)(hf * 64) * lda + ks * 64,
                  ldsAw + (kt & 1) * ABYTES + hf * 64 * 128);
  };
  auto stBh = [&](int kt, int hf) {
    int ks = kt < nk ? kt : nk - 1;
#pragma unroll
    for (int l = 0; l < 2; ++l)
      gload_lds16(Bs + (size_t)(hf * 128 + l * 64) * ldb + ks * 64,
                  ldsBw + (kt & 1) * BBYTES + hf * 128 * 128 + l * 8192);
  };

  const int fr = lane & 15, kq = lane >> 4;
  const int rA = wr * 64 + fr;
  const int rB = wc * 64 + fr;
  unsigned aof[2], bof[2];
  aof[0] = rA * 128 + ((kq ^ (rA & 7)) << 4);
  aof[1] = rA * 128 + (((kq + 4) ^ (rA & 7)) << 4);
  bof[0] = 2 * ABYTES + rB * 128 + ((kq ^ (rB & 7)) << 4);
  bof[1] = 2 * ABYTES + rB * 128 + (((kq + 4) ^ (rB & 7)) << 4);
  constexpr int A0 = 0, A1 = ABYTES, B0 = 0, B1 = BBYTES;

  f32x4 acc[4][4];
#pragma unroll
  for (int m = 0; m < 4; ++m)
#pragma unroll
    for (int n = 0; n < 4; ++n) acc[m][n] = (f32x4){0.f, 0.f, 0.f, 0.f};

  bf16x8 a[QM][2], b0[2][2], b1[2][2];

  stA2(0); stBh(0, 0); stBh(0, 1);
  stA2(1); stBh(1, 0);
  asm volatile("s_waitcnt vmcnt(4)" ::: "memory");
  BAR();

  for (int t = 0; t < niter; ++t) {
    const int ka = 2 * t + 2, kb = 2 * t + 3;
    LDA8(a, 0, A0); LDB8(b0, 0, B0);
    stBh(2 * t + 1, 1);
    BAR(); LGKM0(); PRIO1(); MMQ(a, b0, 0, 0); PRIO0(); BAR();
    LDB8(b1, 1, B0);
    stA2(ka); stBh(ka, 0);
    asm volatile("s_waitcnt vmcnt(4)" ::: "memory");
    BAR(); LGKM0(); PRIO1(); MMQ(a, b1, 0, 1); PRIO0(); BAR();
    LDA8(a, 0, A1); LDB8(b0, 0, B1);
    stBh(ka, 1);
    BAR(); LGKM0(); PRIO1(); MMQ(a, b0, 0, 0); PRIO0(); BAR();
    LDB8(b1, 1, B1);
    stA2(kb); stBh(kb, 0);
    asm volatile("s_waitcnt vmcnt(4)" ::: "memory");
    BAR(); LGKM0(); PRIO1(); MMQ(a, b1, 0, 1); PRIO0(); BAR();
  }
  EPILOGUE(4, 64)
}

// ---------------- row softmax, bf16 scores -> bf16 P in place ----------------
template <bool CAUSAL>
__global__ __launch_bounds__(256) void k_softmax(unsigned short* __restrict__ scores) {
  int row = blockIdx.x;  // b*S + i
  int i = row & (Ss - 1);
  unsigned short* src = scores + (size_t)row * Ss;
  int nv = CAUSAL ? i + 1 : Ss;
  int nb = CAUSAL ? ((i & ~127) + 128) : Ss;
  int t = threadIdx.x;
  int w = t >> 6, lane = t & 63;
  bool act = t * 8 < nb;
  float v[8];
  float mx = -1e30f;
  if (act) {
    u16x8 raw = *(const u16x8*)(src + t * 8);
#pragma unroll
    for (int k = 0; k < 8; k++) {
      int j = t * 8 + k;
      v[k] = (j < nv) ? bf2f(raw[k]) : -1e30f;
      mx = fmaxf(mx, v[k]);
    }
  } else {
#pragma unroll
    for (int k = 0; k < 8; k++) v[k] = -1e30f;
  }
#pragma unroll
  for (int o = 32; o; o >>= 1) mx = fmaxf(mx, __shfl_xor(mx, o));
  __shared__ float red[8];
  if (lane == 0) red[w] = mx;
  __syncthreads();
  mx = fmaxf(fmaxf(red[0], red[1]), fmaxf(red[2], red[3]));
  float sum = 0.f;
#pragma unroll
  for (int k = 0; k < 8; k++) {
    float e = (v[k] > -1e29f) ? __expf(v[k] - mx) : 0.f;
    v[k] = e;
    sum += e;
  }
#pragma unroll
  for (int o = 32; o; o >>= 1) sum += __shfl_xor(sum, o);
  if (lane == 0) red[4 + w] = sum;
  __syncthreads();
  sum = red[4] + red[5] + red[6] + red[7];
  float inv = 1.f / sum;
  if (act) {
    u16x8 r;
#pragma unroll
    for (int k = 0; k < 8; k++) r[k] = f2bf(v[k] * inv);
    *(u16x8*)(src + t * 8) = r;
  }
}

// ---------------- LayerNorm (bf16 input: residual already added) ----------------
__global__ __launch_bounds__(256) void k_ln(const unsigned short* __restrict__ a,
                                            const float* __restrict__ g,
                                            const float* __restrict__ be,
                                            float* __restrict__ outf,
                                            unsigned short* __restrict__ outb) {
  int row = blockIdx.x;
  size_t o = (size_t)row * Dd;
  int t = threadIdx.x;
  u16x4 raw = *(const u16x4*)(a + o + t * 4);
  f32x4 x;
#pragma unroll
  for (int k = 0; k < 4; k++) x[k] = bf2f(raw[k]);
  float s = x[0] + x[1] + x[2] + x[3];
  float q = x[0] * x[0] + x[1] * x[1] + x[2] * x[2] + x[3] * x[3];
  int w = t >> 6, lane = t & 63;
#pragma unroll
  for (int of = 32; of; of >>= 1) {
    s += __shfl_xor(s, of);
    q += __shfl_xor(q, of);
  }
  __shared__ float red[8];
  if (lane == 0) {
    red[w] = s;
    red[4 + w] = q;
  }
  __syncthreads();
  s = red[0] + red[1] + red[2] + red[3];
  q = red[4] + red[5] + red[6] + red[7];
  float mean = s * (1.f / Dd);
  float var = q * (1.f / Dd) - mean * mean;
  float rstd = rsqrtf(var + 1e-5f);
  f32x4 gv = *(const f32x4*)(g + t * 4);
  f32x4 bv = *(const f32x4*)(be + t * 4);
  f32x4 y;
#pragma unroll
  for (int k = 0; k < 4; k++) y[k] = (x[k] - mean) * rstd * gv[k] + bv[k];
  *(f32x4*)(outf + o + t * 4) = y;
  if (outb) {
    u16x4 r;
    r[0] = f2bf(y[0]); r[1] = f2bf(y[1]); r[2] = f2bf(y[2]); r[3] = f2bf(y[3]);
    *(u16x4*)(outb + o + t * 4) = r;
  }
}

extern "C" void kernel_launch(void* const* d_in, const int* in_sizes, int n_in, void* d_out,
                              int out_size, void* d_ws, size_t ws_size, hipStream_t stream) {
  (void)in_sizes; (void)n_in; (void)out_size; (void)ws_size;
  const float* y   = (const float*)d_in[0];
  const float* Z   = (const float*)d_in[1];
  const float* w1  = (const float*)d_in[2];
  const float* b1  = (const float*)d_in[3];
  const float* w2  = (const float*)d_in[4];
  const float* b2  = (const float*)d_in[5];
  const float* g1  = (const float*)d_in[6];
  const float* be1 = (const float*)d_in[7];
  const float* g2  = (const float*)d_in[8];
  const float* be2 = (const float*)d_in[9];
  const float* g3  = (const float*)d_in[10];
  const float* be3 = (const float*)d_in[11];
  float* out = (float*)d_out;

  // ws layout (160 MB), lifetime-audited:
  //  T    @   0 (16MB)  y^T bf16 (dead after PV1); reused as FFN2 bf16 output
  //  Zbf  @  16 (16MB)  Z bf16 row-major (read by sc2)
  //  ybf  @  32 (16MB)  y / y1 / y2 bf16
  //  w1t  @  48 ( 8MB)  w1^T bf16
  //  w2t  @  56 ( 8MB)  w2^T bf16
  //  sc   @  64 (32MB)  scores/P bf16; FFN's h (64MB @64-128) overwrites after PV2
  //  Zt   @  96 (16MB)  Z^T bf16 (read by PV2; overwritten by h after PV2)
  //  res  @ 128 (32MB)  residual stream fp32
  //  attn bf16 scratch = d_out (first 16MB as u16) for LN1/LN2 inputs
  char* ws = (char*)d_ws;
  const size_t MB = 1024ull * 1024ull;
  unsigned short* T   = (unsigned short*)(ws);
  unsigned short* Zbf = (unsigned short*)(ws + 16 * MB);
  unsigned short* ybf = (unsigned short*)(ws + 32 * MB);
  unsigned short* w1t = (unsigned short*)(ws + 48 * MB);
  unsigned short* w2t = (unsigned short*)(ws + 56 * MB);
  unsigned short* sc  = (unsigned short*)(ws + 64 * MB);
  unsigned short* h   = (unsigned short*)(ws + 64 * MB);
  unsigned short* Zt  = (unsigned short*)(ws + 96 * MB);
  float* res          = (float*)(ws + 128 * MB);
  unsigned short* attnb = (unsigned short*)d_out;  // bf16 LN input scratch

  dim3 b256(256), b512(512);
  const float scl = 1.f / 32.f;
  const long SD = (long)Ss * Dd, SS = (long)Ss * Ss;

  // --- all input prep up front (no mid-pipeline bubbles) ---
  k_transpose_cast<<<dim3(Dd / 32, Ss / 32, Bb), dim3(32, 8), 0, stream>>>(y, T, ybf, Ss, Dd);
  k_transpose_cast<<<dim3(Dd / 32, Ss / 32, Bb), dim3(32, 8), 0, stream>>>(Z, Zt, Zbf, Ss, Dd);
  k_transpose_cast<<<dim3(Ff / 32, Dd / 32, 1), dim3(32, 8), 0, stream>>>(w1, w1t, nullptr, Dd, Ff);
  k_transpose_cast<<<dim3(Dd / 32, Ff / 32, 1), dim3(32, 8), 0, stream>>>(w2, w2t, nullptr, Ff, Dd);

  // --- self-attention ---
  k_gemm8<0, true><<<dim3(36, 1, Bb), b512, 0, stream>>>(
      ybf, ybf, sc, nullptr, nullptr, Dd, Dd, Dd, Ss, SD, SD, SS, scl);
  k_softmax<true><<<dim3(Bb * Ss), b256, 0, stream>>>(sc);
  k_gemm4<4, true><<<dim3(Dd / 256, Ss / 128, Bb), b512, 0, stream>>>(
      sc, T, attnb, nullptr, y, Ss, Ss, Ss, Dd, SS, SD, SD, 1.f);
  k_ln<<<dim3(Bb * Ss), b256, 0, stream>>>(attnb, g1, be1, res, ybf);

  // --- cross-attention ---
  k_gemm8<0, false><<<dim3(Ss / 256, Ss / 256, Bb), b512, 0, stream>>>(
      ybf, Zbf, sc, nullptr, nullptr, Dd, Dd, Dd, Ss, SD, SD, SS, scl);
  k_softmax<false><<<dim3(Bb * Ss), b256, 0, stream>>>(sc);
  k_gemm4<4, false><<<dim3(Dd / 256, Ss / 128, Bb), b512, 0, stream>>>(
      sc, Zt, attnb, nullptr, res, Ss, Ss, Ss, Dd, SS, SD, SD, 1.f);
  k_ln<<<dim3(Bb * Ss), b256, 0, stream>>>(attnb, g2, be2, res, ybf);

  // --- FFN --- (h overwrites sc+Zt region; FFN2 bf16 output goes to dead T slot)
  k_gemm8<2, false><<<dim3(Ff / 256, (Bb * Ss) / 256, 1), b512, 0, stream>>>(
      ybf, w1t, h, b1, nullptr, Dd, Dd, Dd, Ff, 0L, 0L, 0L, 1.f);
  k_gemm4<5, false><<<dim3(Dd / 256, (Bb * Ss) / 128, 1), b512, 0, stream>>>(
      h, w2t, T, b2, res, Ff, Ff, Ff, Dd, 0L, 0L, 0L, 1.f);
  k_ln<<<dim3(Bb * Ss), b256, 0, stream>>>(T, g3, be3, out, nullptr);
}

// Round 9
// 376.343 us; speedup vs baseline: 2.8944x; 1.0068x over previous
//
#include <hip/hip_runtime.h>
#include <hip/hip_bf16.h>

// DecoderBlock: B=4, S=2048, D=1024, DFF=4096. fp32 in/out, bf16 MFMA internals.
// Round 9: read-one-phase-ahead fragment pipeline in both GEMMs — each phase
// issues the ds_reads for the NEXT phase's MFMA (quadrant order 00,10,01,11),
// gate phases read the next buffer after vmcnt+barrier, and explicit
// lgkmcnt(0) is removed so the compiler emits counted lgkm waits that leave
// look-ahead reads in flight (LDS drain overlaps MFMA).

#define Bb 4
#define Ss 2048
#define Dd 1024
#define Ff 4096

typedef __attribute__((ext_vector_type(4))) float f32x4;
typedef __attribute__((ext_vector_type(8))) short bf16x8;
typedef __attribute__((ext_vector_type(8))) unsigned short u16x8;
typedef __attribute__((ext_vector_type(4))) unsigned short u16x4;

__device__ __forceinline__ unsigned short f2bf(float f) {
  unsigned u = __float_as_uint(f);
  u += 0x7FFFu + ((u >> 16) & 1u);
  return (unsigned short)(u >> 16);
}
__device__ __forceinline__ float bf2f(unsigned short h) {
  return __uint_as_float(((unsigned)h) << 16);
}

__device__ __forceinline__ void gload_lds16(const void* g, void* l) {
  __builtin_amdgcn_global_load_lds((const __attribute__((address_space(1))) void*)g,
                                   (__attribute__((address_space(3))) void*)l, 16, 0, 0);
}

__device__ __forceinline__ int xcd8(int orig, int n) {
  int q = n >> 3, r = n & 7;
  int x = orig & 7;
  int base = x < r ? x * (q + 1) : r * (q + 1) + (x - r) * q;
  return base + (orig >> 3);
}

// ---------------- transpose+cast: in[R][C] fp32 -> outT[C][R] bf16 (+opt outR bf16) ----
__global__ __launch_bounds__(256) void k_transpose_cast(const float* __restrict__ in,
                                                        unsigned short* __restrict__ outT,
                                                        unsigned short* __restrict__ outR,
                                                        int R, int C) {
  __shared__ float t[32][33];
  size_t bo = (size_t)blockIdx.z * R * C;
  const float* pin = in + bo;
  unsigned short* poutT = outT + bo;
  unsigned short* poutR = outR ? outR + bo : nullptr;
  int c0 = blockIdx.x * 32, r0 = blockIdx.y * 32;
  int tx = threadIdx.x, ty = threadIdx.y;
#pragma unroll
  for (int i = 0; i < 4; i++) {
    float v = pin[(size_t)(r0 + ty + i * 8) * C + c0 + tx];
    t[ty + i * 8][tx] = v;
    if (poutR) poutR[(size_t)(r0 + ty + i * 8) * C + c0 + tx] = f2bf(v);
  }
  __syncthreads();
#pragma unroll
  for (int i = 0; i < 4; i++)
    poutT[(size_t)(c0 + ty + i * 8) * R + r0 + tx] = f2bf(t[tx][ty + i * 8]);
}

// ---- shared GEMM machinery --------------------------------------------------
// EPI: 0 *scale->bf16 | 2 bias+relu->bf16 | 4 (v+resid)->bf16 | 5 (v+bias+resid)->bf16
#define BAR() __builtin_amdgcn_s_barrier()
#define PRIO1() __builtin_amdgcn_s_setprio(1)
#define PRIO0() __builtin_amdgcn_s_setprio(0)

#define LDA8(arr, mh, bo)                                                       \
  {                                                                             \
    _Pragma("unroll") for (int j_ = 0; j_ < QM; ++j_) {                         \
      _Pragma("unroll") for (int kh_ = 0; kh_ < 2; ++kh_) {                     \
        arr[j_][kh_] =                                                          \
            *(const bf16x8*)(lds + (bo) + ((mh)*QM + j_) * 2048 + aof[kh_]);    \
      }                                                                         \
    }                                                                           \
  }

#define LDB8(arr, nh, bo)                                                       \
  {                                                                             \
    _Pragma("unroll") for (int n_ = 0; n_ < 2; ++n_) {                          \
      _Pragma("unroll") for (int kh_ = 0; kh_ < 2; ++kh_) {                     \
        arr[n_][kh_] =                                                          \
            *(const bf16x8*)(lds + (bo) + ((nh)*2 + n_) * 2048 + bof[kh_]);     \
      }                                                                         \
    }                                                                           \
  }

#define MMQ(aarr, barr, mh, nh)                                                 \
  {                                                                             \
    _Pragma("unroll") for (int j_ = 0; j_ < QM; ++j_) {                         \
      _Pragma("unroll") for (int n_ = 0; n_ < 2; ++n_) {                        \
        _Pragma("unroll") for (int kh_ = 0; kh_ < 2; ++kh_) {                   \
          acc[(mh)*QM + j_][(nh)*2 + n_] = __builtin_amdgcn_mfma_f32_16x16x32_bf16( \
              aarr[j_][kh_], barr[n_][kh_], acc[(mh)*QM + j_][(nh)*2 + n_], 0, 0, 0); \
        }                                                                       \
      }                                                                         \
    }                                                                           \
  }

#define EPILOGUE(MR_, WMS_)                                                     \
  {                                                                             \
    const int colb = j0 + wc * 64 + fr;                                         \
    const int rowb = i0 + wr * (WMS_) + (kq << 2);                              \
    const size_t cb = (size_t)bz * bsC;                                         \
    _Pragma("unroll") for (int m = 0; m < (MR_); ++m) {                         \
      _Pragma("unroll") for (int r = 0; r < 4; ++r) {                           \
        size_t ro = cb + (size_t)(rowb + m * 16 + r) * ldc;                     \
        _Pragma("unroll") for (int n = 0; n < 4; ++n) {                         \
          float v = acc[m][n][r];                                               \
          int col = colb + n * 16;                                              \
          if (EPI == 0) Cb[ro + col] = f2bf(v * scale);                         \
          else if (EPI == 2) Cb[ro + col] = f2bf(fmaxf(v + bias[col], 0.f));    \
          else if (EPI == 4) Cb[ro + col] = f2bf(v + resid[ro + col]);          \
          else Cb[ro + col] = f2bf(v + bias[col] + resid[ro + col]);            \
        }                                                                       \
      }                                                                         \
    }                                                                           \
  }

// ========================= k_gemm8: BMt=256, 8-phase, read-ahead =============
template <int EPI, bool CAUSAL>
__global__ __launch_bounds__(512) void k_gemm8(
    const unsigned short* __restrict__ Ag, const unsigned short* __restrict__ Bg,
    unsigned short* __restrict__ Cb,
    const float* __restrict__ bias, const float* __restrict__ resid,
    int K, int lda, int ldb, int ldc, long bsA, long bsB, long bsC, float scale) {
  constexpr int QM = 4;
  constexpr int ABYTES = 32768, BBYTES = 32768;
  __shared__ alignas(16) char lds[2 * ABYTES + 2 * BBYTES];

  int i0, j0;
  if (CAUSAL) {
    int t = xcd8(blockIdx.x, gridDim.x);
    int ti = (int)((sqrtf(8.f * t + 1.f) - 1.f) * 0.5f);
    while ((ti + 1) * (ti + 2) / 2 <= t) ++ti;
    while (ti * (ti + 1) / 2 > t) --ti;
    i0 = ti * 256;
    j0 = (t - ti * (ti + 1) / 2) * 256;
  } else {
    int lin = xcd8(blockIdx.y * gridDim.x + blockIdx.x, gridDim.x * gridDim.y);
    i0 = (lin / gridDim.x) * 256;
    j0 = (lin % gridDim.x) * 256;
  }
  int bz = blockIdx.z;
  Ag += (size_t)bz * bsA;
  Bg += (size_t)bz * bsB;

  const int nk = K / 64;
  const int niter = nk / 2;

  const int tid = threadIdx.x;
  const int w = tid >> 6, lane = tid & 63;
  const int wr = w >> 2, wc = w & 3;

  const int srow = (w << 3) + (lane >> 3);
  const int bcs = (lane & 7) ^ (lane >> 3);
  const unsigned short* As = Ag + (size_t)(i0 + srow) * lda + bcs * 8;
  const unsigned short* Bs = Bg + (size_t)(j0 + srow) * ldb + bcs * 8;
  char* ldsAw = lds + w * 1024;
  char* ldsBw = lds + 2 * ABYTES + w * 1024;

  auto stA = [&](int kt, int hf) {
    int ks = kt < nk ? kt : nk - 1;
#pragma unroll
    for (int l = 0; l < 2; ++l)
      gload_lds16(As + (size_t)(hf * 128 + l * 64) * lda + ks * 64,
                  ldsAw + (kt & 1) * ABYTES + hf * 128 * 128 + l * 8192);
  };
  auto stB = [&](int kt, int hf) {
    int ks = kt < nk ? kt : nk - 1;
#pragma unroll
    for (int l = 0; l < 2; ++l)
      gload_lds16(Bs + (size_t)(hf * 128 + l * 64) * ldb + ks * 64,
                  ldsBw + (kt & 1) * BBYTES + hf * 128 * 128 + l * 8192);
  };

  const int fr = lane & 15, kq = lane >> 4;
  const int rA = wr * 128 + fr;
  const int rB = wc * 64 + fr;
  unsigned aof[2], bof[2];
  aof[0] = rA * 128 + ((kq ^ (rA & 7)) << 4);
  aof[1] = rA * 128 + (((kq + 4) ^ (rA & 7)) << 4);
  bof[0] = 2 * ABYTES + rB * 128 + ((kq ^ (rB & 7)) << 4);
  bof[1] = 2 * ABYTES + rB * 128 + (((kq + 4) ^ (rB & 7)) << 4);
  constexpr int A0 = 0, A1 = ABYTES, B0 = 0, B1 = BBYTES;

  f32x4 acc[8][4];
#pragma unroll
  for (int m = 0; m < 8; ++m)
#pragma unroll
    for (int n = 0; n < 4; ++n) acc[m][n] = (f32x4){0.f, 0.f, 0.f, 0.f};

  bf16x8 a0[QM][2], a1[QM][2], b0[2][2], b1[2][2];

  // prologue: 7 half-tiles; vmcnt(6) drains tile0; pre-read ph1 operands (a0,b0)
  stA(0, 0); stA(0, 1); stB(0, 0); stB(0, 1);
  stA(1, 0); stA(1, 1); stB(1, 0);
  asm volatile("s_waitcnt vmcnt(6)" ::: "memory");
  BAR();
  LDA8(a0, 0, A0); LDB8(b0, 0, B0);

  // Read-ahead schedule (reads in phase P feed phase P+1's MFMA):
  //  ph1: rd a1(buf0)       | ph2: rd b1(buf0) | ph3: -        | ph4: GATE, rd a0,b0(buf1)
  //  ph5: rd a1(buf1)       | ph6: rd b1(buf1) | ph7: -        | ph8: GATE, rd a0,b0(buf0')
  // MFMA: ph1(a0,b0) ph2(a1,b0) ph3(a0,b1) ph4(a1,b1) then same on buf1.
  // Reg liveness: a0 dead after ph3 -> reload ph4; b0 dead after ph2 -> reload ph4;
  // a1 dead after ph4 -> reload ph5; b1 dead after ph4 -> reload ph6. No conflicts.
  // Slot WAR (stage >=1 barrier after slot's last frag read):
  //  buf0-A last read ph1 (a1) -> stA(ka,*) ph2/ph3 OK; buf0-B last read ph2 (b1)
  //  -> stB(ka,*) ph4/ph5 OK; buf1-A last read ph5 -> stA(kb,*) ph6/ph7 OK;
  //  buf1-B last read ph6 -> stB(kb,0) ph8, stB(2t+3,1) next-ph1 OK.
  // Buf visibility: buf1 reads only after ph4's vmcnt+BAR; buf0' after ph8's.
  for (int t = 0; t < niter; ++t) {
    const int ka = 2 * t + 2, kb = 2 * t + 3;
    // ph1
    LDA8(a1, 1, A0);
    stB(2 * t + 1, 1);
    BAR(); PRIO1(); MMQ(a0, b0, 0, 0); PRIO0(); BAR();
    // ph2
    LDB8(b1, 1, B0);
    stA(ka, 0);
    BAR(); PRIO1(); MMQ(a1, b0, 1, 0); PRIO0(); BAR();
    // ph3
    stA(ka, 1);
    BAR(); PRIO1(); MMQ(a0, b1, 0, 1); PRIO0(); BAR();
    // ph4: GATE tile(2t+1); then buf1 pre-reads drain under MFMA
    stB(ka, 0);
    asm volatile("s_waitcnt vmcnt(6)" ::: "memory");
    BAR();
    LDA8(a0, 0, A1); LDB8(b0, 0, B1);
    PRIO1(); MMQ(a1, b1, 1, 1); PRIO0(); BAR();
    // ph5
    LDA8(a1, 1, A1);
    stB(ka, 1);
    BAR(); PRIO1(); MMQ(a0, b0, 0, 0); PRIO0(); BAR();
    // ph6
    LDB8(b1, 1, B1);
    stA(kb, 0);
    BAR(); PRIO1(); MMQ(a1, b0, 1, 0); PRIO0(); BAR();
    // ph7
    stA(kb, 1);
    BAR(); PRIO1(); MMQ(a0, b1, 0, 1); PRIO0(); BAR();
    // ph8: GATE tile(ka); buf0-new pre-reads
    stB(kb, 0);
    asm volatile("s_waitcnt vmcnt(6)" ::: "memory");
    BAR();
    LDA8(a0, 0, A0); LDB8(b0, 0, B0);
    PRIO1(); MMQ(a1, b1, 1, 1); PRIO0(); BAR();
  }
  EPILOGUE(8, 128)
}

// ========================= k_gemm4: BMt=128, 4-phase, read-ahead =============
template <int EPI, bool KCAP>
__global__ __launch_bounds__(512) void k_gemm4(
    const unsigned short* __restrict__ Ag, const unsigned short* __restrict__ Bg,
    unsigned short* __restrict__ Cb,
    const float* __restrict__ bias, const float* __restrict__ resid,
    int K, int lda, int ldb, int ldc, long bsA, long bsB, long bsC, float scale) {
  constexpr int QM = 4;
  constexpr int ABYTES = 16384, BBYTES = 32768;
  __shared__ alignas(16) char lds[2 * ABYTES + 2 * BBYTES];

  int lin = xcd8(blockIdx.y * gridDim.x + blockIdx.x, gridDim.x * gridDim.y);
  int i0 = (lin / gridDim.x) * 128;
  int j0 = (lin % gridDim.x) * 256;
  int bz = blockIdx.z;
  Ag += (size_t)bz * bsA;
  Bg += (size_t)bz * bsB;

  int nk = K / 64;
  if (KCAP) {
    int cap = i0 / 64 + 2;
    nk = nk < cap ? nk : cap;
  }
  const int niter = nk / 2;

  const int tid = threadIdx.x;
  const int w = tid >> 6, lane = tid & 63;
  const int wr = w >> 2, wc = w & 3;

  const int srow = (w << 3) + (lane >> 3);
  const int bcs = (lane & 7) ^ (lane >> 3);
  const unsigned short* As = Ag + (size_t)(i0 + srow) * lda + bcs * 8;
  const unsigned short* Bs = Bg + (size_t)(j0 + srow) * ldb + bcs * 8;
  char* ldsAw = lds + w * 1024;
  char* ldsBw = lds + 2 * ABYTES + w * 1024;

  auto stA2 = [&](int kt) {
    int ks = kt < nk ? kt : nk - 1;
#pragma unroll
    for (int hf = 0; hf < 2; ++hf)
      gload_lds16(As + (size_t)(hf * 64) * lda + ks * 64,
                  ldsAw + (kt & 1) * ABYTES + hf * 64 * 128);
  };
  auto stBh = [&](int kt, int hf) {
    int ks = kt < nk ? kt : nk - 1;
#pragma unroll
    for (int l = 0; l < 2; ++l)
      gload_lds16(Bs + (size_t)(hf * 128 + l * 64) * ldb + ks * 64,
                  ldsBw + (kt & 1) * BBYTES + hf * 128 * 128 + l * 8192);
  };

  const int fr = lane & 15, kq = lane >> 4;
  const int rA = wr * 64 + fr;
  const int rB = wc * 64 + fr;
  unsigned aof[2], bof[2];
  aof[0] = rA * 128 + ((kq ^ (rA & 7)) << 4);
  aof[1] = rA * 128 + (((kq + 4) ^ (rA & 7)) << 4);
  bof[0] = 2 * ABYTES + rB * 128 + ((kq ^ (rB & 7)) << 4);
  bof[1] = 2 * ABYTES + rB * 128 + (((kq + 4) ^ (rB & 7)) << 4);
  constexpr int A0 = 0, A1 = ABYTES, B0 = 0, B1 = BBYTES;

  f32x4 acc[4][4];
#pragma unroll
  for (int m = 0; m < 4; ++m)
#pragma unroll
    for (int n = 0; n < 4; ++n) acc[m][n] = (f32x4){0.f, 0.f, 0.f, 0.f};

  bf16x8 a[QM][2], b0[2][2], b1[2][2];

  // prologue: tile0 + A(1)+B(1)h0; vmcnt(4) drains tile0; pre-read a,b0 (buf0)
  stA2(0); stBh(0, 0); stBh(0, 1);
  stA2(1); stBh(1, 0);
  asm volatile("s_waitcnt vmcnt(4)" ::: "memory");
  BAR();
  LDA8(a, 0, A0); LDB8(b0, 0, B0);

  // ph1: rd b1(buf0); MFMA(a,b0) | ph2: GATE; MFMA(a,b1); rd a,b0(buf1)
  // ph3: rd b1(buf1); MFMA(a,b0') | ph4: GATE; MFMA(a,b1'); rd a,b0(buf0')
  // a/b0 reload after their gate-phase MFMA (program order resolves reg WAR).
  for (int t = 0; t < niter; ++t) {
    const int ka = 2 * t + 2, kb = 2 * t + 3;
    // ph1
    LDB8(b1, 1, B0);
    stBh(2 * t + 1, 1);
    BAR(); PRIO1(); MMQ(a, b0, 0, 0); PRIO0(); BAR();
    // ph2: GATE tile(2t+1)
    stA2(ka); stBh(ka, 0);
    asm volatile("s_waitcnt vmcnt(4)" ::: "memory");
    BAR();
    PRIO1(); MMQ(a, b1, 0, 1); PRIO0();
    LDA8(a, 0, A1); LDB8(b0, 0, B1);
    BAR();
    // ph3
    LDB8(b1, 1, B1);
    stBh(ka, 1);
    BAR(); PRIO1(); MMQ(a, b0, 0, 0); PRIO0(); BAR();
    // ph4: GATE tile(ka)
    stA2(kb); stBh(kb, 0);
    asm volatile("s_waitcnt vmcnt(4)" ::: "memory");
    BAR();
    PRIO1(); MMQ(a, b1, 0, 1); PRIO0();
    LDA8(a, 0, A0); LDB8(b0, 0, B0);
    BAR();
  }
  EPILOGUE(4, 64)
}

// ---------------- row softmax, bf16 scores -> bf16 P in place ----------------
template <bool CAUSAL>
__global__ __launch_bounds__(256) void k_softmax(unsigned short* __restrict__ scores) {
  int row = blockIdx.x;  // b*S + i
  int i = row & (Ss - 1);
  unsigned short* src = scores + (size_t)row * Ss;
  int nv = CAUSAL ? i + 1 : Ss;
  int nb = CAUSAL ? ((i & ~127) + 128) : Ss;
  int t = threadIdx.x;
  int w = t >> 6, lane = t & 63;
  bool act = t * 8 < nb;
  float v[8];
  float mx = -1e30f;
  if (act) {
    u16x8 raw = *(const u16x8*)(src + t * 8);
#pragma unroll
    for (int k = 0; k < 8; k++) {
      int j = t * 8 + k;
      v[k] = (j < nv) ? bf2f(raw[k]) : -1e30f;
      mx = fmaxf(mx, v[k]);
    }
  } else {
#pragma unroll
    for (int k = 0; k < 8; k++) v[k] = -1e30f;
  }
#pragma unroll
  for (int o = 32; o; o >>= 1) mx = fmaxf(mx, __shfl_xor(mx, o));
  __shared__ float red[8];
  if (lane == 0) red[w] = mx;
  __syncthreads();
  mx = fmaxf(fmaxf(red[0], red[1]), fmaxf(red[2], red[3]));
  float sum = 0.f;
#pragma unroll
  for (int k = 0; k < 8; k++) {
    float e = (v[k] > -1e29f) ? __expf(v[k] - mx) : 0.f;
    v[k] = e;
    sum += e;
  }
#pragma unroll
  for (int o = 32; o; o >>= 1) sum += __shfl_xor(sum, o);
  if (lane == 0) red[4 + w] = sum;
  __syncthreads();
  sum = red[4] + red[5] + red[6] + red[7];
  float inv = 1.f / sum;
  if (act) {
    u16x8 r;
#pragma unroll
    for (int k = 0; k < 8; k++) r[k] = f2bf(v[k] * inv);
    *(u16x8*)(src + t * 8) = r;
  }
}

// ---------------- LayerNorm (bf16 input: residual already added) ----------------
__global__ __launch_bounds__(256) void k_ln(const unsigned short* __restrict__ a,
                                            const float* __restrict__ g,
                                            const float* __restrict__ be,
                                            float* __restrict__ outf,
                                            unsigned short* __restrict__ outb) {
  int row = blockIdx.x;
  size_t o = (size_t)row * Dd;
  int t = threadIdx.x;
  u16x4 raw = *(const u16x4*)(a + o + t * 4);
  f32x4 x;
#pragma unroll
  for (int k = 0; k < 4; k++) x[k] = bf2f(raw[k]);
  float s = x[0] + x[1] + x[2] + x[3];
  float q = x[0] * x[0] + x[1] * x[1] + x[2] * x[2] + x[3] * x[3];
  int w = t >> 6, lane = t & 63;
#pragma unroll
  for (int of = 32; of; of >>= 1) {
    s += __shfl_xor(s, of);
    q += __shfl_xor(q, of);
  }
  __shared__ float red[8];
  if (lane == 0) {
    red[w] = s;
    red[4 + w] = q;
  }
  __syncthreads();
  s = red[0] + red[1] + red[2] + red[3];
  q = red[4] + red[5] + red[6] + red[7];
  float mean = s * (1.f / Dd);
  float var = q * (1.f / Dd) - mean * mean;
  float rstd = rsqrtf(var + 1e-5f);
  f32x4 gv = *(const f32x4*)(g + t * 4);
  f32x4 bv = *(const f32x4*)(be + t * 4);
  f32x4 y;
#pragma unroll
  for (int k = 0; k < 4; k++) y[k] = (x[k] - mean) * rstd * gv[k] + bv[k];
  *(f32x4*)(outf + o + t * 4) = y;
  if (outb) {
    u16x4 r;
    r[0] = f2bf(y[0]); r[1] = f2bf(y[1]); r[2] = f2bf(y[2]); r[3] = f2bf(y[3]);
    *(u16x4*)(outb + o + t * 4) = r;
  }
}

extern "C" void kernel_launch(void* const* d_in, const int* in_sizes, int n_in, void* d_out,
                              int out_size, void* d_ws, size_t ws_size, hipStream_t stream) {
  (void)in_sizes; (void)n_in; (void)out_size; (void)ws_size;
  const float* y   = (const float*)d_in[0];
  const float* Z   = (const float*)d_in[1];
  const float* w1  = (const float*)d_in[2];
  const float* b1  = (const float*)d_in[3];
  const float* w2  = (const float*)d_in[4];
  const float* b2  = (const float*)d_in[5];
  const float* g1  = (const float*)d_in[6];
  const float* be1 = (const float*)d_in[7];
  const float* g2  = (const float*)d_in[8];
  const float* be2 = (const float*)d_in[9];
  const float* g3  = (const float*)d_in[10];
  const float* be3 = (const float*)d_in[11];
  float* out = (float*)d_out;

  // ws layout (160 MB), lifetime-audited (same as R8):
  char* ws = (char*)d_ws;
  const size_t MB = 1024ull * 1024ull;
  unsigned short* T   = (unsigned short*)(ws);
  unsigned short* Zbf = (unsigned short*)(ws + 16 * MB);
  unsigned short* ybf = (unsigned short*)(ws + 32 * MB);
  unsigned short* w1t = (unsigned short*)(ws + 48 * MB);
  unsigned short* w2t = (unsigned short*)(ws + 56 * MB);
  unsigned short* sc  = (unsigned short*)(ws + 64 * MB);
  unsigned short* h   = (unsigned short*)(ws + 64 * MB);
  unsigned short* Zt  = (unsigned short*)(ws + 96 * MB);
  float* res          = (float*)(ws + 128 * MB);
  unsigned short* attnb = (unsigned short*)d_out;

  dim3 b256(256), b512(512);
  const float scl = 1.f / 32.f;
  const long SD = (long)Ss * Dd, SS = (long)Ss * Ss;

  // --- all input prep up front ---
  k_transpose_cast<<<dim3(Dd / 32, Ss / 32, Bb), dim3(32, 8), 0, stream>>>(y, T, ybf, Ss, Dd);
  k_transpose_cast<<<dim3(Dd / 32, Ss / 32, Bb), dim3(32, 8), 0, stream>>>(Z, Zt, Zbf, Ss, Dd);
  k_transpose_cast<<<dim3(Ff / 32, Dd / 32, 1), dim3(32, 8), 0, stream>>>(w1, w1t, nullptr, Dd, Ff);
  k_transpose_cast<<<dim3(Dd / 32, Ff / 32, 1), dim3(32, 8), 0, stream>>>(w2, w2t, nullptr, Ff, Dd);

  // --- self-attention ---
  k_gemm8<0, true><<<dim3(36, 1, Bb), b512, 0, stream>>>(
      ybf, ybf, sc, nullptr, nullptr, Dd, Dd, Dd, Ss, SD, SD, SS, scl);
  k_softmax<true><<<dim3(Bb * Ss), b256, 0, stream>>>(sc);
  k_gemm4<4, true><<<dim3(Dd / 256, Ss / 128, Bb), b512, 0, stream>>>(
      sc, T, attnb, nullptr, y, Ss, Ss, Ss, Dd, SS, SD, SD, 1.f);
  k_ln<<<dim3(Bb * Ss), b256, 0, stream>>>(attnb, g1, be1, res, ybf);

  // --- cross-attention ---
  k_gemm8<0, false><<<dim3(Ss / 256, Ss / 256, Bb), b512, 0, stream>>>(
      ybf, Zbf, sc, nullptr, nullptr, Dd, Dd, Dd, Ss, SD, SD, SS, scl);
  k_softmax<false><<<dim3(Bb * Ss), b256, 0, stream>>>(sc);
  k_gemm4<4, false><<<dim3(Dd / 256, Ss / 128, Bb), b512, 0, stream>>>(
      sc, Zt, attnb, nullptr, res, Ss, Ss, Ss, Dd, SS, SD, SD, 1.f);
  k_ln<<<dim3(Bb * Ss), b256, 0, stream>>>(attnb, g2, be2, res, ybf);

  // --- FFN ---
  k_gemm8<2, false><<<dim3(Ff / 256, (Bb * Ss) / 256, 1), b512, 0, stream>>>(
      ybf, w1t, h, b1, nullptr, Dd, Dd, Dd, Ff, 0L, 0L, 0L, 1.f);
  k_gemm4<5, false><<<dim3(Dd / 256, (Bb * Ss) / 128, 1), b512, 0, stream>>>(
      h, w2t, T, b2, res, Ff, Ff, Ff, Dd, 0L, 0L, 0L, 1.f);
  k_ln<<<dim3(Bb * Ss), b256, 0, stream>>>(T, g3, be3, out, nullptr);
}

// Round 10
// 367.146 us; speedup vs baseline: 2.9669x; 1.0250x over previous
//
#include <hip/hip_runtime.h>
#include <hip/hip_bf16.h>
#include <hip/hip_fp8.h>

// DecoderBlock: B=4, S=2048, D=1024, DFF=4096. fp32 in/out.
// Round 10: score GEMMs in fp8 e4m3 (halved LDS bytes/staging/FETCH on the
// LDS-serial-bound phases). bf16 GEMMs (PV/FFN) and their R9 schedule frozen.

#define Bb 4
#define Ss 2048
#define Dd 1024
#define Ff 4096

typedef __attribute__((ext_vector_type(4))) float f32x4;
typedef __attribute__((ext_vector_type(8))) short bf16x8;
typedef __attribute__((ext_vector_type(2))) long i64x2;
typedef __attribute__((ext_vector_type(8))) unsigned short u16x8;
typedef __attribute__((ext_vector_type(4))) unsigned short u16x4;

__device__ __forceinline__ unsigned short f2bf(float f) {
  unsigned u = __float_as_uint(f);
  u += 0x7FFFu + ((u >> 16) & 1u);
  return (unsigned short)(u >> 16);
}
__device__ __forceinline__ float bf2f(unsigned short h) {
  return __uint_as_float(((unsigned)h) << 16);
}
__device__ __forceinline__ unsigned char f2f8(float f) {
  __hip_fp8_e4m3 q(f);
  return q.__x;
}
// fp8 buffer column permutation: within each 64B row-group, octet o -> phys
// 2*(o&3)+(o>>2)  (pairs (kq, kq+4) adjacent -> one b128 = both K-windows)
__device__ __forceinline__ int f8col(int c) {
  int g = c >> 6, b = c & 63, o = b >> 3, j = b & 7;
  return g * 64 + (2 * (o & 3) + (o >> 2)) * 8 + j;
}

__device__ __forceinline__ void gload_lds16(const void* g, void* l) {
  __builtin_amdgcn_global_load_lds((const __attribute__((address_space(1))) void*)g,
                                   (__attribute__((address_space(3))) void*)l, 16, 0, 0);
}

__device__ __forceinline__ int xcd8(int orig, int n) {
  int q = n >> 3, r = n & 7;
  int x = orig & 7;
  int base = x < r ? x * (q + 1) : r * (q + 1) + (x - r) * q;
  return base + (orig >> 3);
}

// ---------------- transpose+cast: in[R][C] fp32 -> outT[C][R] bf16 (+opt fp8 row-major) --
__global__ __launch_bounds__(256) void k_transpose_cast(const float* __restrict__ in,
                                                        unsigned short* __restrict__ outT,
                                                        unsigned char* __restrict__ out8,
                                                        int R, int C) {
  __shared__ float t[32][33];
  size_t bo = (size_t)blockIdx.z * R * C;
  const float* pin = in + bo;
  unsigned short* poutT = outT + bo;
  unsigned char* pout8 = out8 ? out8 + bo : nullptr;
  int c0 = blockIdx.x * 32, r0 = blockIdx.y * 32;
  int tx = threadIdx.x, ty = threadIdx.y;
#pragma unroll
  for (int i = 0; i < 4; i++) {
    float v = pin[(size_t)(r0 + ty + i * 8) * C + c0 + tx];
    t[ty + i * 8][tx] = v;
    if (pout8) pout8[(size_t)(r0 + ty + i * 8) * C + f8col(c0 + tx)] = f2f8(v);
  }
  __syncthreads();
#pragma unroll
  for (int i = 0; i < 4; i++)
    poutT[(size_t)(c0 + ty + i * 8) * R + r0 + tx] = f2bf(t[tx][ty + i * 8]);
}

// ---- shared machinery --------------------------------------------------
#define BAR() __builtin_amdgcn_s_barrier()
#define PRIO1() __builtin_amdgcn_s_setprio(1)
#define PRIO0() __builtin_amdgcn_s_setprio(0)

#define LDA8(arr, mh, bo)                                                       \
  {                                                                             \
    _Pragma("unroll") for (int j_ = 0; j_ < QM; ++j_) {                         \
      _Pragma("unroll") for (int kh_ = 0; kh_ < 2; ++kh_) {                     \
        arr[j_][kh_] =                                                          \
            *(const bf16x8*)(lds + (bo) + ((mh)*QM + j_) * 2048 + aof[kh_]);    \
      }                                                                         \
    }                                                                           \
  }

#define LDB8(arr, nh, bo)                                                       \
  {                                                                             \
    _Pragma("unroll") for (int n_ = 0; n_ < 2; ++n_) {                          \
      _Pragma("unroll") for (int kh_ = 0; kh_ < 2; ++kh_) {                     \
        arr[n_][kh_] =                                                          \
            *(const bf16x8*)(lds + (bo) + ((nh)*2 + n_) * 2048 + bof[kh_]);     \
      }                                                                         \
    }                                                                           \
  }

#define MMQ(aarr, barr, mh, nh)                                                 \
  {                                                                             \
    _Pragma("unroll") for (int j_ = 0; j_ < QM; ++j_) {                         \
      _Pragma("unroll") for (int n_ = 0; n_ < 2; ++n_) {                        \
        _Pragma("unroll") for (int kh_ = 0; kh_ < 2; ++kh_) {                   \
          acc[(mh)*QM + j_][(nh)*2 + n_] = __builtin_amdgcn_mfma_f32_16x16x32_bf16( \
              aarr[j_][kh_], barr[n_][kh_], acc[(mh)*QM + j_][(nh)*2 + n_], 0, 0, 0); \
        }                                                                       \
      }                                                                         \
    }                                                                           \
  }

// fp8 variants (i64x2 frags: [0]=K-window0, [1]=K-window1)
#define LDAF8(arr, mh, bo)                                                      \
  {                                                                             \
    _Pragma("unroll") for (int j_ = 0; j_ < 4; ++j_)                            \
        arr[j_] = *(const i64x2*)(lds + (bo) + ((mh)*4 + j_) * 1024 + aofs);    \
  }
#define LDBF8(arr, nh, bo)                                                      \
  {                                                                             \
    _Pragma("unroll") for (int n_ = 0; n_ < 2; ++n_)                            \
        arr[n_] = *(const i64x2*)(lds + (bo) + ((nh)*2 + n_) * 1024 + bofs);    \
  }
#define MMQF8(aarr, barr, mh, nh)                                               \
  {                                                                             \
    _Pragma("unroll") for (int j_ = 0; j_ < 4; ++j_) {                          \
      _Pragma("unroll") for (int n_ = 0; n_ < 2; ++n_) {                        \
        _Pragma("unroll") for (int kh_ = 0; kh_ < 2; ++kh_) {                   \
          acc[(mh)*4 + j_][(nh)*2 + n_] = __builtin_amdgcn_mfma_f32_16x16x32_fp8_fp8( \
              aarr[j_][kh_], barr[n_][kh_], acc[(mh)*4 + j_][(nh)*2 + n_], 0, 0, 0);  \
        }                                                                       \
      }                                                                         \
    }                                                                           \
  }

#define EPILOGUE(MR_, WMS_)                                                     \
  {                                                                             \
    const int colb = j0 + wc * 64 + fr;                                         \
    const int rowb = i0 + wr * (WMS_) + (kq << 2);                              \
    const size_t cb = (size_t)bz * bsC;                                         \
    _Pragma("unroll") for (int m = 0; m < (MR_); ++m) {                         \
      _Pragma("unroll") for (int r = 0; r < 4; ++r) {                           \
        size_t ro = cb + (size_t)(rowb + m * 16 + r) * ldc;                     \
        _Pragma("unroll") for (int n = 0; n < 4; ++n) {                         \
          float v = acc[m][n][r];                                               \
          int col = colb + n * 16;                                              \
          if (EPI == 0) Cb[ro + col] = f2bf(v * scale);                         \
          else if (EPI == 2) Cb[ro + col] = f2bf(fmaxf(v + bias[col], 0.f));    \
          else if (EPI == 4) Cb[ro + col] = f2bf(v + resid[ro + col]);          \
          else Cb[ro + col] = f2bf(v + bias[col] + resid[ro + col]);            \
        }                                                                       \
      }                                                                         \
    }                                                                           \
  }

// ========================= k_gemm8f8: fp8 scores, 256x256, 8-phase ===========
// LDS rows = 64B (64 fp8, BK=64). Buffer pre-interleaved (f8col) so one
// ds_read_b128 per frag delivers both K-windows; chunk16 XOR c^((r>>1)&3)
// is conflict-free at 8-lane b128 batches. Staging: 1 gload/half-tile,
// linear dest + inverse-swizzled source. Gates vmcnt(3) at ph4/ph8.
template <bool CAUSAL>
__global__ __launch_bounds__(512) void k_gemm8f8(
    const unsigned char* __restrict__ Ag, const unsigned char* __restrict__ Bg,
    unsigned short* __restrict__ Cb,
    int K, int lda, int ldb, int ldc, long bsA, long bsB, long bsC, float scale) {
  constexpr int ABYTES = 16384, BBYTES = 16384;
  __shared__ alignas(16) char lds[2 * ABYTES + 2 * BBYTES];  // 64 KB

  int i0, j0;
  if (CAUSAL) {
    int t = xcd8(blockIdx.x, gridDim.x);
    int ti = (int)((sqrtf(8.f * t + 1.f) - 1.f) * 0.5f);
    while ((ti + 1) * (ti + 2) / 2 <= t) ++ti;
    while (ti * (ti + 1) / 2 > t) --ti;
    i0 = ti * 256;
    j0 = (t - ti * (ti + 1) / 2) * 256;
  } else {
    int lin = xcd8(blockIdx.y * gridDim.x + blockIdx.x, gridDim.x * gridDim.y);
    i0 = (lin / gridDim.x) * 256;
    j0 = (lin % gridDim.x) * 256;
  }
  int bz = blockIdx.z;
  Ag += (size_t)bz * bsA;
  Bg += (size_t)bz * bsB;

  const int nk = K / 64;
  const int niter = nk / 2;

  const int tid = threadIdx.x;
  const int w = tid >> 6, lane = tid & 63;
  const int wr = w >> 2, wc = w & 3;

  // staging: lane -> (row = tid>>2 within half-tile, chunk16 = tid&3);
  // source chunk = (tid&3) ^ ((row>>1)&3) = (tid&3) ^ ((tid>>3)&3)
  const int srow = tid >> 2;
  const int scs = (tid & 3) ^ ((tid >> 3) & 3);
  const unsigned char* As = Ag + (size_t)(i0 + srow) * lda + scs * 16;
  const unsigned char* Bs = Bg + (size_t)(j0 + srow) * ldb + scs * 16;

  auto stA = [&](int kt, int hf) {
    int ks = kt < nk ? kt : nk - 1;
    gload_lds16(As + (size_t)(hf * 128) * lda + ks * 64,
                lds + (kt & 1) * ABYTES + hf * 8192 + w * 1024);
  };
  auto stB = [&](int kt, int hf) {
    int ks = kt < nk ? kt : nk - 1;
    gload_lds16(Bs + (size_t)(hf * 128) * ldb + ks * 64,
                lds + 2 * ABYTES + (kt & 1) * BBYTES + hf * 8192 + w * 1024);
  };

  const int fr = lane & 15, kq = lane >> 4;
  const int rA = wr * 128 + fr;
  const int rB = wc * 64 + fr;
  const unsigned aofs = rA * 64 + ((kq ^ ((rA >> 1) & 3)) << 4);
  const unsigned bofs = rB * 64 + ((kq ^ ((rB >> 1) & 3)) << 4);
  constexpr int A0 = 0, A1 = ABYTES, B0 = 2 * ABYTES, B1 = 2 * ABYTES + BBYTES;

  f32x4 acc[8][4];
#pragma unroll
  for (int m = 0; m < 8; ++m)
#pragma unroll
    for (int n = 0; n < 4; ++n) acc[m][n] = (f32x4){0.f, 0.f, 0.f, 0.f};

  i64x2 a0[4], a1[4], b0[2], b1[2];

  // prologue: 7 half-tiles (1 instr each); vmcnt(3) drains tile0's 4
  stA(0, 0); stA(0, 1); stB(0, 0); stB(0, 1);
  stA(1, 0); stA(1, 1); stB(1, 0);
  asm volatile("s_waitcnt vmcnt(3)" ::: "memory");
  BAR();
  LDAF8(a0, 0, A0); LDBF8(b0, 0, B0);

  // R9 read-ahead schedule; stage placement slot-identical to R6/R9 audit.
  for (int t = 0; t < niter; ++t) {
    const int ka = 2 * t + 2, kb = 2 * t + 3;
    // ph1
    LDAF8(a1, 1, A0);
    stB(2 * t + 1, 1);
    BAR(); PRIO1(); MMQF8(a0, b0, 0, 0); PRIO0(); BAR();
    // ph2
    LDBF8(b1, 1, B0);
    stA(ka, 0);
    BAR(); PRIO1(); MMQF8(a1, b0, 1, 0); PRIO0(); BAR();
    // ph3
    stA(ka, 1);
    BAR(); PRIO1(); MMQF8(a0, b1, 0, 1); PRIO0(); BAR();
    // ph4: GATE tile(2t+1); buf1 pre-reads drain under MFMA
    stB(ka, 0);
    asm volatile("s_waitcnt vmcnt(3)" ::: "memory");
    BAR();
    LDAF8(a0, 0, A1); LDBF8(b0, 0, B1);
    PRIO1(); MMQF8(a1, b1, 1, 1); PRIO0(); BAR();
    // ph5
    LDAF8(a1, 1, A1);
    stB(ka, 1);
    BAR(); PRIO1(); MMQF8(a0, b0, 0, 0); PRIO0(); BAR();
    // ph6
    LDBF8(b1, 1, B1);
    stA(kb, 0);
    BAR(); PRIO1(); MMQF8(a1, b0, 1, 0); PRIO0(); BAR();
    // ph7
    stA(kb, 1);
    BAR(); PRIO1(); MMQF8(a0, b1, 0, 1); PRIO0(); BAR();
    // ph8: GATE tile(ka)
    stB(kb, 0);
    asm volatile("s_waitcnt vmcnt(3)" ::: "memory");
    BAR();
    LDAF8(a0, 0, A0); LDBF8(b0, 0, B0);
    PRIO1(); MMQF8(a1, b1, 1, 1); PRIO0(); BAR();
  }

  // epilogue: scores -> bf16 (*scale); C/D layout shape-determined (same as bf16)
  const int colb = j0 + wc * 64 + fr;
  const int rowb = i0 + wr * 128 + (kq << 2);
  const size_t cb = (size_t)bz * bsC;
#pragma unroll
  for (int m = 0; m < 8; ++m) {
#pragma unroll
    for (int r = 0; r < 4; ++r) {
      size_t ro = cb + (size_t)(rowb + m * 16 + r) * ldc;
#pragma unroll
      for (int n = 0; n < 4; ++n)
        Cb[ro + colb + n * 16] = f2bf(acc[m][n][r] * scale);
    }
  }
}

// ========================= k_gemm8: BMt=256, 8-phase bf16 (R9, frozen) =======
template <int EPI, bool CAUSAL>
__global__ __launch_bounds__(512) void k_gemm8(
    const unsigned short* __restrict__ Ag, const unsigned short* __restrict__ Bg,
    unsigned short* __restrict__ Cb,
    const float* __restrict__ bias, const float* __restrict__ resid,
    int K, int lda, int ldb, int ldc, long bsA, long bsB, long bsC, float scale) {
  constexpr int QM = 4;
  constexpr int ABYTES = 32768, BBYTES = 32768;
  __shared__ alignas(16) char lds[2 * ABYTES + 2 * BBYTES];

  int i0, j0;
  if (CAUSAL) {
    int t = xcd8(blockIdx.x, gridDim.x);
    int ti = (int)((sqrtf(8.f * t + 1.f) - 1.f) * 0.5f);
    while ((ti + 1) * (ti + 2) / 2 <= t) ++ti;
    while (ti * (ti + 1) / 2 > t) --ti;
    i0 = ti * 256;
    j0 = (t - ti * (ti + 1) / 2) * 256;
  } else {
    int lin = xcd8(blockIdx.y * gridDim.x + blockIdx.x, gridDim.x * gridDim.y);
    i0 = (lin / gridDim.x) * 256;
    j0 = (lin % gridDim.x) * 256;
  }
  int bz = blockIdx.z;
  Ag += (size_t)bz * bsA;
  Bg += (size_t)bz * bsB;

  const int nk = K / 64;
  const int niter = nk / 2;

  const int tid = threadIdx.x;
  const int w = tid >> 6, lane = tid & 63;
  const int wr = w >> 2, wc = w & 3;

  const int srow = (w << 3) + (lane >> 3);
  const int bcs = (lane & 7) ^ (lane >> 3);
  const unsigned short* As = Ag + (size_t)(i0 + srow) * lda + bcs * 8;
  const unsigned short* Bs = Bg + (size_t)(j0 + srow) * ldb + bcs * 8;
  char* ldsAw = lds + w * 1024;
  char* ldsBw = lds + 2 * ABYTES + w * 1024;

  auto stA = [&](int kt, int hf) {
    int ks = kt < nk ? kt : nk - 1;
#pragma unroll
    for (int l = 0; l < 2; ++l)
      gload_lds16(As + (size_t)(hf * 128 + l * 64) * lda + ks * 64,
                  ldsAw + (kt & 1) * ABYTES + hf * 128 * 128 + l * 8192);
  };
  auto stB = [&](int kt, int hf) {
    int ks = kt < nk ? kt : nk - 1;
#pragma unroll
    for (int l = 0; l < 2; ++l)
      gload_lds16(Bs + (size_t)(hf * 128 + l * 64) * ldb + ks * 64,
                  ldsBw + (kt & 1) * BBYTES + hf * 128 * 128 + l * 8192);
  };

  const int fr = lane & 15, kq = lane >> 4;
  const int rA = wr * 128 + fr;
  const int rB = wc * 64 + fr;
  unsigned aof[2], bof[2];
  aof[0] = rA * 128 + ((kq ^ (rA & 7)) << 4);
  aof[1] = rA * 128 + (((kq + 4) ^ (rA & 7)) << 4);
  bof[0] = 2 * ABYTES + rB * 128 + ((kq ^ (rB & 7)) << 4);
  bof[1] = 2 * ABYTES + rB * 128 + (((kq + 4) ^ (rB & 7)) << 4);
  constexpr int A0 = 0, A1 = ABYTES, B0 = 0, B1 = BBYTES;

  f32x4 acc[8][4];
#pragma unroll
  for (int m = 0; m < 8; ++m)
#pragma unroll
    for (int n = 0; n < 4; ++n) acc[m][n] = (f32x4){0.f, 0.f, 0.f, 0.f};

  bf16x8 a0[QM][2], a1[QM][2], b0[2][2], b1[2][2];

  stA(0, 0); stA(0, 1); stB(0, 0); stB(0, 1);
  stA(1, 0); stA(1, 1); stB(1, 0);
  asm volatile("s_waitcnt vmcnt(6)" ::: "memory");
  BAR();
  LDA8(a0, 0, A0); LDB8(b0, 0, B0);

  for (int t = 0; t < niter; ++t) {
    const int ka = 2 * t + 2, kb = 2 * t + 3;
    LDA8(a1, 1, A0);
    stB(2 * t + 1, 1);
    BAR(); PRIO1(); MMQ(a0, b0, 0, 0); PRIO0(); BAR();
    LDB8(b1, 1, B0);
    stA(ka, 0);
    BAR(); PRIO1(); MMQ(a1, b0, 1, 0); PRIO0(); BAR();
    stA(ka, 1);
    BAR(); PRIO1(); MMQ(a0, b1, 0, 1); PRIO0(); BAR();
    stB(ka, 0);
    asm volatile("s_waitcnt vmcnt(6)" ::: "memory");
    BAR();
    LDA8(a0, 0, A1); LDB8(b0, 0, B1);
    PRIO1(); MMQ(a1, b1, 1, 1); PRIO0(); BAR();
    LDA8(a1, 1, A1);
    stB(ka, 1);
    BAR(); PRIO1(); MMQ(a0, b0, 0, 0); PRIO0(); BAR();
    LDB8(b1, 1, B1);
    stA(kb, 0);
    BAR(); PRIO1(); MMQ(a1, b0, 1, 0); PRIO0(); BAR();
    stA(kb, 1);
    BAR(); PRIO1(); MMQ(a0, b1, 0, 1); PRIO0(); BAR();
    stB(kb, 0);
    asm volatile("s_waitcnt vmcnt(6)" ::: "memory");
    BAR();
    LDA8(a0, 0, A0); LDB8(b0, 0, B0);
    PRIO1(); MMQ(a1, b1, 1, 1); PRIO0(); BAR();
  }
  EPILOGUE(8, 128)
}

// ========================= k_gemm4: BMt=128, 4-phase bf16 (R9, frozen) =======
template <int EPI, bool KCAP>
__global__ __launch_bounds__(512) void k_gemm4(
    const unsigned short* __restrict__ Ag, const unsigned short* __restrict__ Bg,
    unsigned short* __restrict__ Cb,
    const float* __restrict__ bias, const float* __restrict__ resid,
    int K, int lda, int ldb, int ldc, long bsA, long bsB, long bsC, float scale) {
  constexpr int QM = 4;
  constexpr int ABYTES = 16384, BBYTES = 32768;
  __shared__ alignas(16) char lds[2 * ABYTES + 2 * BBYTES];

  int lin = xcd8(blockIdx.y * gridDim.x + blockIdx.x, gridDim.x * gridDim.y);
  int i0 = (lin / gridDim.x) * 128;
  int j0 = (lin % gridDim.x) * 256;
  int bz = blockIdx.z;
  Ag += (size_t)bz * bsA;
  Bg += (size_t)bz * bsB;

  int nk = K / 64;
  if (KCAP) {
    int cap = i0 / 64 + 2;
    nk = nk < cap ? nk : cap;
  }
  const int niter = nk / 2;

  const int tid = threadIdx.x;
  const int w = tid >> 6, lane = tid & 63;
  const int wr = w >> 2, wc = w & 3;

  const int srow = (w << 3) + (lane >> 3);
  const int bcs = (lane & 7) ^ (lane >> 3);
  const unsigned short* As = Ag + (size_t)(i0 + srow) * lda + bcs * 8;
  const unsigned short* Bs = Bg + (size_t)(j0 + srow) * ldb + bcs * 8;
  char* ldsAw = lds + w * 1024;
  char* ldsBw = lds + 2 * ABYTES + w * 1024;

  auto stA2 = [&](int kt) {
    int ks = kt < nk ? kt : nk - 1;
#pragma unroll
    for (int hf = 0; hf < 2; ++hf)
      gload_lds16(As + (size_t)(hf * 64) * lda + ks * 64,
                  ldsAw + (kt & 1) * ABYTES + hf * 64 * 128);
  };
  auto stBh = [&](int kt, int hf) {
    int ks = kt < nk ? kt : nk - 1;
#pragma unroll
    for (int l = 0; l < 2; ++l)
      gload_lds16(Bs + (size_t)(hf * 128 + l * 64) * ldb + ks * 64,
                  ldsBw + (kt & 1) * BBYTES + hf * 128 * 128 + l * 8192);
  };

  const int fr = lane & 15, kq = lane >> 4;
  const int rA = wr * 64 + fr;
  const int rB = wc * 64 + fr;
  unsigned aof[2], bof[2];
  aof[0] = rA * 128 + ((kq ^ (rA & 7)) << 4);
  aof[1] = rA * 128 + (((kq + 4) ^ (rA & 7)) << 4);
  bof[0] = 2 * ABYTES + rB * 128 + ((kq ^ (rB & 7)) << 4);
  bof[1] = 2 * ABYTES + rB * 128 + (((kq + 4) ^ (rB & 7)) << 4);
  constexpr int A0 = 0, A1 = ABYTES, B0 = 0, B1 = BBYTES;

  f32x4 acc[4][4];
#pragma unroll
  for (int m = 0; m < 4; ++m)
#pragma unroll
    for (int n = 0; n < 4; ++n) acc[m][n] = (f32x4){0.f, 0.f, 0.f, 0.f};

  bf16x8 a[QM][2], b0[2][2], b1[2][2];

  stA2(0); stBh(0, 0); stBh(0, 1);
  stA2(1); stBh(1, 0);
  asm volatile("s_waitcnt vmcnt(4)" ::: "memory");
  BAR();
  LDA8(a, 0, A0); LDB8(b0, 0, B0);

  for (int t = 0; t < niter; ++t) {
    const int ka = 2 * t + 2, kb = 2 * t + 3;
    LDB8(b1, 1, B0);
    stBh(2 * t + 1, 1);
    BAR(); PRIO1(); MMQ(a, b0, 0, 0); PRIO0(); BAR();
    stA2(ka); stBh(ka, 0);
    asm volatile("s_waitcnt vmcnt(4)" ::: "memory");
    BAR();
    PRIO1(); MMQ(a, b1, 0, 1); PRIO0();
    LDA8(a, 0, A1); LDB8(b0, 0, B1);
    BAR();
    LDB8(b1, 1, B1);
    stBh(ka, 1);
    BAR(); PRIO1(); MMQ(a, b0, 0, 0); PRIO0(); BAR();
    stA2(kb); stBh(kb, 0);
    asm volatile("s_waitcnt vmcnt(4)" ::: "memory");
    BAR();
    PRIO1(); MMQ(a, b1, 0, 1); PRIO0();
    LDA8(a, 0, A0); LDB8(b0, 0, B0);
    BAR();
  }
  EPILOGUE(4, 64)
}

// ---------------- row softmax, bf16 scores -> bf16 P in place ----------------
template <bool CAUSAL>
__global__ __launch_bounds__(256) void k_softmax(unsigned short* __restrict__ scores) {
  int row = blockIdx.x;  // b*S + i
  int i = row & (Ss - 1);
  unsigned short* src = scores + (size_t)row * Ss;
  int nv = CAUSAL ? i + 1 : Ss;
  int nb = CAUSAL ? ((i & ~127) + 128) : Ss;
  int t = threadIdx.x;
  int w = t >> 6, lane = t & 63;
  bool act = t * 8 < nb;
  float v[8];
  float mx = -1e30f;
  if (act) {
    u16x8 raw = *(const u16x8*)(src + t * 8);
#pragma unroll
    for (int k = 0; k < 8; k++) {
      int j = t * 8 + k;
      v[k] = (j < nv) ? bf2f(raw[k]) : -1e30f;
      mx = fmaxf(mx, v[k]);
    }
  } else {
#pragma unroll
    for (int k = 0; k < 8; k++) v[k] = -1e30f;
  }
#pragma unroll
  for (int o = 32; o; o >>= 1) mx = fmaxf(mx, __shfl_xor(mx, o));
  __shared__ float red[8];
  if (lane == 0) red[w] = mx;
  __syncthreads();
  mx = fmaxf(fmaxf(red[0], red[1]), fmaxf(red[2], red[3]));
  float sum = 0.f;
#pragma unroll
  for (int k = 0; k < 8; k++) {
    float e = (v[k] > -1e29f) ? __expf(v[k] - mx) : 0.f;
    v[k] = e;
    sum += e;
  }
#pragma unroll
  for (int o = 32; o; o >>= 1) sum += __shfl_xor(sum, o);
  if (lane == 0) red[4 + w] = sum;
  __syncthreads();
  sum = red[4] + red[5] + red[6] + red[7];
  float inv = 1.f / sum;
  if (act) {
    u16x8 r;
#pragma unroll
    for (int k = 0; k < 8; k++) r[k] = f2bf(v[k] * inv);
    *(u16x8*)(src + t * 8) = r;
  }
}

// ---------------- LayerNorm (bf16 input) -> fp32 + optional bf16/fp8 ----------
// OM: 0 none | 1 bf16 | 2 fp8 (interleaved f8col layout)
template <int OM>
__global__ __launch_bounds__(256) void k_ln(const unsigned short* __restrict__ a,
                                            const float* __restrict__ g,
                                            const float* __restrict__ be,
                                            float* __restrict__ outf,
                                            unsigned short* __restrict__ outb,
                                            unsigned char* __restrict__ out8) {
  int row = blockIdx.x;
  size_t o = (size_t)row * Dd;
  int t = threadIdx.x;
  u16x4 raw = *(const u16x4*)(a + o + t * 4);
  f32x4 x;
#pragma unroll
  for (int k = 0; k < 4; k++) x[k] = bf2f(raw[k]);
  float s = x[0] + x[1] + x[2] + x[3];
  float q = x[0] * x[0] + x[1] * x[1] + x[2] * x[2] + x[3] * x[3];
  int w = t >> 6, lane = t & 63;
#pragma unroll
  for (int of = 32; of; of >>= 1) {
    s += __shfl_xor(s, of);
    q += __shfl_xor(q, of);
  }
  __shared__ float red[8];
  if (lane == 0) {
    red[w] = s;
    red[4 + w] = q;
  }
  __syncthreads();
  s = red[0] + red[1] + red[2] + red[3];
  q = red[4] + red[5] + red[6] + red[7];
  float mean = s * (1.f / Dd);
  float var = q * (1.f / Dd) - mean * mean;
  float rstd = rsqrtf(var + 1e-5f);
  f32x4 gv = *(const f32x4*)(g + t * 4);
  f32x4 bv = *(const f32x4*)(be + t * 4);
  f32x4 y;
#pragma unroll
  for (int k = 0; k < 4; k++) y[k] = (x[k] - mean) * rstd * gv[k] + bv[k];
  *(f32x4*)(outf + o + t * 4) = y;
  if (OM == 1) {
    u16x4 r;
    r[0] = f2bf(y[0]); r[1] = f2bf(y[1]); r[2] = f2bf(y[2]); r[3] = f2bf(y[3]);
    *(u16x4*)(outb + o + t * 4) = r;
  } else if (OM == 2) {
    // elements 4t..4t+3 share one octet half: compute phys addr once
    int cbyte = t * 4;
    int gq = cbyte >> 6, oo = (cbyte >> 3) & 7, j = cbyte & 7;  // j in {0,4}
    int phys = gq * 64 + (2 * (oo & 3) + (oo >> 2)) * 8 + j;
    unsigned r = (unsigned)f2f8(y[0]) | ((unsigned)f2f8(y[1]) << 8) |
                 ((unsigned)f2f8(y[2]) << 16) | ((unsigned)f2f8(y[3]) << 24);
    *(unsigned*)(out8 + (size_t)row * Dd + phys) = r;
  }
}

extern "C" void kernel_launch(void* const* d_in, const int* in_sizes, int n_in, void* d_out,
                              int out_size, void* d_ws, size_t ws_size, hipStream_t stream) {
  (void)in_sizes; (void)n_in; (void)out_size; (void)ws_size;
  const float* y   = (const float*)d_in[0];
  const float* Z   = (const float*)d_in[1];
  const float* w1  = (const float*)d_in[2];
  const float* b1  = (const float*)d_in[3];
  const float* w2  = (const float*)d_in[4];
  const float* b2  = (const float*)d_in[5];
  const float* g1  = (const float*)d_in[6];
  const float* be1 = (const float*)d_in[7];
  const float* g2  = (const float*)d_in[8];
  const float* be2 = (const float*)d_in[9];
  const float* g3  = (const float*)d_in[10];
  const float* be3 = (const float*)d_in[11];
  float* out = (float*)d_out;

  // ws layout (160MB), lifetime-audited:
  //  T   @  0  (16MB) y^T bf16 (PV1 B; dead after) -> FFN2 bf16 out (LN3 in)
  //  Zt  @ 16  (16MB) Z^T bf16 (PV2 B)
  //  ybf @ 32  (16MB) y2 bf16 (LN2 out -> FFN1 A)
  //  w1t @ 48  ( 8MB), w2t @ 56 (8MB)
  //  sc  @ 64  (32MB) scores/P bf16 (dead after PV2)
  //  y8  @ 96  ( 8MB) y fp8 (self-scores A,B; dead after)
  //  Z8  @104  ( 8MB) Z fp8 (cross B; dead after cross-scores)
  //  y18 @112  ( 8MB) y1 fp8 (cross A; dead after cross-scores)
  //  h   @ 64  (64MB) FFN1 out bf16 — overwrites sc/y8/Z8/y18 (all dead)
  //  res @128  (32MB) residual fp32 (PV2 resid, then LN2 rewrites for FFN2 resid)
  //  attnb = d_out (bf16 LN1/LN2 input scratch)
  char* ws = (char*)d_ws;
  const size_t MB = 1024ull * 1024ull;
  unsigned short* T   = (unsigned short*)(ws);
  unsigned short* Zt  = (unsigned short*)(ws + 16 * MB);
  unsigned short* ybf = (unsigned short*)(ws + 32 * MB);
  unsigned short* w1t = (unsigned short*)(ws + 48 * MB);
  unsigned short* w2t = (unsigned short*)(ws + 56 * MB);
  unsigned short* sc  = (unsigned short*)(ws + 64 * MB);
  unsigned short* h   = (unsigned short*)(ws + 64 * MB);
  unsigned char* y8   = (unsigned char*)(ws + 96 * MB);
  unsigned char* Z8   = (unsigned char*)(ws + 104 * MB);
  unsigned char* y18  = (unsigned char*)(ws + 112 * MB);
  float* res          = (float*)(ws + 128 * MB);
  unsigned short* attnb = (unsigned short*)d_out;

  dim3 b256(256), b512(512);
  const float scl = 1.f / 32.f;
  const long SD = (long)Ss * Dd, SS = (long)Ss * Ss;

  // --- input prep up front ---
  k_transpose_cast<<<dim3(Dd / 32, Ss / 32, Bb), dim3(32, 8), 0, stream>>>(y, T, y8, Ss, Dd);
  k_transpose_cast<<<dim3(Dd / 32, Ss / 32, Bb), dim3(32, 8), 0, stream>>>(Z, Zt, Z8, Ss, Dd);
  k_transpose_cast<<<dim3(Ff / 32, Dd / 32, 1), dim3(32, 8), 0, stream>>>(w1, w1t, nullptr, Dd, Ff);
  k_transpose_cast<<<dim3(Dd / 32, Ff / 32, 1), dim3(32, 8), 0, stream>>>(w2, w2t, nullptr, Ff, Dd);

  // --- self-attention (scores in fp8) ---
  k_gemm8f8<true><<<dim3(36, 1, Bb), b512, 0, stream>>>(
      y8, y8, sc, Dd, Dd, Dd, Ss, SD, SD, SS, scl);
  k_softmax<true><<<dim3(Bb * Ss), b256, 0, stream>>>(sc);
  k_gemm4<4, true><<<dim3(Dd / 256, Ss / 128, Bb), b512, 0, stream>>>(
      sc, T, attnb, nullptr, y, Ss, Ss, Ss, Dd, SS, SD, SD, 1.f);
  k_ln<2><<<dim3(Bb * Ss), b256, 0, stream>>>(attnb, g1, be1, res, nullptr, y18);

  // --- cross-attention (scores in fp8) ---
  k_gemm8f8<false><<<dim3(Ss / 256, Ss / 256, Bb), b512, 0, stream>>>(
      y18, Z8, sc, Dd, Dd, Dd, Ss, SD, SD, SS, scl);
  k_softmax<false><<<dim3(Bb * Ss), b256, 0, stream>>>(sc);
  k_gemm4<4, false><<<dim3(Dd / 256, Ss / 128, Bb), b512, 0, stream>>>(
      sc, Zt, attnb, nullptr, res, Ss, Ss, Ss, Dd, SS, SD, SD, 1.f);
  k_ln<1><<<dim3(Bb * Ss), b256, 0, stream>>>(attnb, g2, be2, res, ybf, nullptr);

  // --- FFN (bf16, frozen) ---
  k_gemm8<2, false><<<dim3(Ff / 256, (Bb * Ss) / 256, 1), b512, 0, stream>>>(
      ybf, w1t, h, b1, nullptr, Dd, Dd, Dd, Ff, 0L, 0L, 0L, 1.f);
  k_gemm4<5, false><<<dim3(Dd / 256, (Bb * Ss) / 128, 1), b512, 0, stream>>>(
      h, w2t, T, b2, res, Ff, Ff, Ff, Dd, 0L, 0L, 0L, 1.f);
  k_ln<0><<<dim3(Bb * Ss), b256, 0, stream>>>(T, g3, be3, out, nullptr, nullptr);
}